// Round 10
// baseline (22675.175 us; speedup 1.0000x reference)
//
#include <hip/hip_runtime.h>
#include <hip/hip_bf16.h>

// Problem: B=4, S=2048, D=1024, INNER=2048, STATE=512.
// out = out_proj(scan(in_proj(hidden)));  scan folded via Wcomb = Wsp @ Wup.
// Round 10 = round-9 (PASS, 13.9ms) + ONE protocol change: sentinel-in-data.
// mixedg pre-filled with MAGIC (0x7F7F7F7F, impossible bf16 pair for |v|<1);
// writers publish 8B returning atomic swaps and post NO flag; readers stage
// region t-1 by polling it with agent-scope 8B atomic loads until all chunks
// are non-MAGIC (the poll IS the stage). Removes drain+counter+flag RTTs.
// Dot / nonlinearity / token prefetch byte-identical to round 9.

#define S_LEN 2048
#define NBATCH 4
#define NBLK 256
#define LSTR 2056      // padded LDS row stride in bf16 (4112 B, 16B-aligned)
#define MAGIC 0x7F7F7F7Fu

typedef __attribute__((ext_vector_type(4))) float f32x4;
typedef __attribute__((ext_vector_type(8))) short bf16x8;

__device__ __forceinline__ unsigned short f2bf(float f) {
  unsigned u = __builtin_bit_cast(unsigned, f);
  u += 0x7FFFu + ((u >> 16) & 1u);
  return (unsigned short)(u >> 16);
}
__device__ __forceinline__ float b2f(unsigned short s) { return __builtin_bit_cast(float, (unsigned)s << 16); }

__device__ __forceinline__ float wave_sum64(float v) {
#pragma unroll
  for (int m = 32; m >= 1; m >>= 1) v += __shfl_xor(v, m, 64);
  return v;
}

#define WAIT_LGKM0() asm volatile("s_waitcnt lgkmcnt(0)" ::: "memory")

// ---------------- fp32 -> bf16 convert (8 elems/thread) ----------------
__global__ void conv_f32_bf16(const float* __restrict__ in, unsigned short* __restrict__ out, int n8) {
  int g = blockIdx.x * 256 + threadIdx.x;
  if (g >= n8) return;
  const float4* p = (const float4*)in + 2 * (size_t)g;
  float4 a = p[0], b = p[1];
  uint4 o;
  o.x = (unsigned)f2bf(a.x) | ((unsigned)f2bf(a.y) << 16);
  o.y = (unsigned)f2bf(a.z) | ((unsigned)f2bf(a.w) << 16);
  o.z = (unsigned)f2bf(b.x) | ((unsigned)f2bf(b.y) << 16);
  o.w = (unsigned)f2bf(b.z) | ((unsigned)f2bf(b.w) << 16);
  ((uint4*)out)[g] = o;
}

// ---------------- Wup [512][2048] -> WupT bf16 [2048][512] ----------------
__global__ void transpose_wup(const float* __restrict__ in, unsigned short* __restrict__ out) {
  int g = blockIdx.x * 256 + threadIdx.x; // over 2048*512
  int i = g >> 9, k = g & 511;
  out[g] = f2bf(in[(size_t)k * 2048 + i]);
}

// ---------------- b_comb[j] = b_sp[j] + sum_k Wsp[j,k]*b_up[k] ----------------
__global__ void bcomb_kernel(const float* __restrict__ wsp, const float* __restrict__ bsp,
                             const float* __restrict__ bup, float* __restrict__ bcomb) {
  int wv = (blockIdx.x * 256 + threadIdx.x) >> 6;
  int lane = threadIdx.x & 63;
  if (wv >= 4096) return;
  float s = 0.f;
  for (int k = lane; k < 512; k += 64) s += wsp[(size_t)wv * 512 + k] * bup[k];
  s = wave_sum64(s);
  if (lane == 0) bcomb[wv] = s + bsp[wv];
}

// ---------------- sp0[b][j] = b_sp[j] + sum_k state0[b,k]*Wsp[j,k] ----------------
__global__ void sp0_kernel(const float* __restrict__ wsp, const float* __restrict__ bsp,
                           const float* __restrict__ state0, float* __restrict__ sp0) {
  int wv = (blockIdx.x * 256 + threadIdx.x) >> 6;
  int lane = threadIdx.x & 63;
  if (wv >= 4096) return;
  float acc[NBATCH] = {0.f, 0.f, 0.f, 0.f};
  for (int k = lane; k < 512; k += 64) {
    float w = wsp[(size_t)wv * 512 + k];
#pragma unroll
    for (int bb = 0; bb < NBATCH; ++bb) acc[bb] += state0[bb * 512 + k] * w;
  }
#pragma unroll
  for (int bb = 0; bb < NBATCH; ++bb) acc[bb] = wave_sum64(acc[bb]);
  if (lane == 0) {
    float b = bsp[wv];
#pragma unroll
    for (int bb = 0; bb < NBATCH; ++bb) sp0[bb * 4096 + wv] = acc[bb] + b;
  }
}

// ---------------- final_state[b][j] = b_up[j] + sum_i mixed[2047,b,i]*Wup[j,i] ----------------
__global__ void final_state_kernel(const float* __restrict__ wup, const float* __restrict__ bup,
                                   const unsigned short* __restrict__ mixedg, float* __restrict__ dst) {
  int wv = (blockIdx.x * 256 + threadIdx.x) >> 6;
  int lane = threadIdx.x & 63;
  if (wv >= 512) return;
  float acc[NBATCH] = {0.f, 0.f, 0.f, 0.f};
  for (int i = lane; i < 2048; i += 64) {
    float w = wup[(size_t)wv * 2048 + i];
#pragma unroll
    for (int bb = 0; bb < NBATCH; ++bb)
      acc[bb] += b2f(mixedg[((size_t)2047 * 4 + bb) * 2048 + i]) * w;
  }
#pragma unroll
  for (int bb = 0; bb < NBATCH; ++bb) acc[bb] = wave_sum64(acc[bb]);
  if (lane == 0) {
    float b = bup[wv];
#pragma unroll
    for (int bb = 0; bb < NBATCH; ++bb) dst[bb * 512 + wv] = acc[bb] + b;
  }
}

// ---------------- bf16 BT-GEMM: C[M,N] = A[M,K] @ B[N,K]^T (+bias) ----------------
// MODE 0: bf16 out + bias; MODE 1: bf16 out, no bias; MODE 2: fp32 out, bias,
// row remap m=s*4+b -> out[b][s][n] (S=2048, N=1024 hardcoded for out_proj).
template <int MODE>
__global__ __launch_bounds__(256) void gemm_bt(
    const unsigned short* __restrict__ A, const unsigned short* __restrict__ B,
    unsigned short* __restrict__ Cbf, float* __restrict__ Cf32,
    const float* __restrict__ bias, int M, int N, int K) {
  const int tm = blockIdx.x * 128, tn = blockIdx.y * 128;
  __shared__ __align__(16) unsigned short At[128][72];
  __shared__ __align__(16) unsigned short Bt[128][72];
  const int tid = threadIdx.x, lane = tid & 63, w = tid >> 6;
  const int wm = (w >> 1) * 64, wn = (w & 1) * 64;
  f32x4 acc[4][4];
#pragma unroll
  for (int a = 0; a < 4; ++a)
#pragma unroll
    for (int b = 0; b < 4; ++b) acc[a][b] = (f32x4)0.f;

  for (int k0 = 0; k0 < K; k0 += 64) {
#pragma unroll
    for (int it = 0; it < 4; ++it) {
      int c = tid + it * 256;
      int r = c >> 3, kp = (c & 7) * 8;
      *(uint4*)&At[r][kp] = *(const uint4*)&A[(size_t)(tm + r) * K + k0 + kp];
      *(uint4*)&Bt[r][kp] = *(const uint4*)&B[(size_t)(tn + r) * K + k0 + kp];
    }
    __syncthreads();
#pragma unroll
    for (int kk = 0; kk < 2; ++kk) {
      bf16x8 af[4], bfr[4];
#pragma unroll
      for (int fm = 0; fm < 4; ++fm)
        af[fm] = *(const bf16x8*)&At[wm + fm * 16 + (lane & 15)][(kk << 5) + ((lane >> 4) << 3)];
#pragma unroll
      for (int fn = 0; fn < 4; ++fn)
        bfr[fn] = *(const bf16x8*)&Bt[wn + fn * 16 + (lane & 15)][(kk << 5) + ((lane >> 4) << 3)];
#pragma unroll
      for (int fm = 0; fm < 4; ++fm)
#pragma unroll
        for (int fn = 0; fn < 4; ++fn)
          acc[fm][fn] = __builtin_amdgcn_mfma_f32_16x16x32_bf16(af[fm], bfr[fn], acc[fm][fn], 0, 0, 0);
    }
    __syncthreads();
  }
  // epilogue
  float bv[4];
#pragma unroll
  for (int fn = 0; fn < 4; ++fn) {
    if constexpr (MODE != 1) bv[fn] = bias[tn + wn + fn * 16 + (lane & 15)];
    else bv[fn] = 0.f;
  }
#pragma unroll
  for (int fm = 0; fm < 4; ++fm)
#pragma unroll
    for (int fn = 0; fn < 4; ++fn)
#pragma unroll
      for (int r = 0; r < 4; ++r) {
        int row = tm + wm + fm * 16 + ((lane >> 4) << 2) + r;
        int col = tn + wn + fn * 16 + (lane & 15);
        float v = acc[fm][fn][r] + bv[fn];
        if constexpr (MODE == 2) {
          Cf32[(size_t)(((row & 3) << 11) + (row >> 2)) * 1024 + col] = v;
        } else {
          Cbf[(size_t)row * N + col] = f2bf(v);
        }
      }
}

// ---------------- persistent scan kernel (single wave per block) ----------------
// 256 blocks x 64 threads, 1 block/CU. Block b owns INNER slice [8b, 8b+8).
// Sentinel protocol: mixedg pre-filled with MAGIC dwords. Per step:
//   poll-stage region t-1 with agent-scope 8B atomic loads (poll IS stage),
//   MFMA dot (padded LDS, r9-identical), nonlinearity, publish slice as
//   8 x 8B returning atomic swaps. No drain, no counter, no flag.
__global__ __launch_bounds__(64, 1) void scan_kernel(
    const unsigned short* __restrict__ wcombg,  // [4096][2048] bf16
    const float* __restrict__ bcombg,           // [4096]
    const float* __restrict__ sp0g,             // [4][4096]
    const unsigned short* __restrict__ projg,   // [8192][6144] bf16, m=b*2048+s
    unsigned short* __restrict__ mixedg)        // [2048][4][2048] bf16, MAGIC-filled
{
  __shared__ __align__(16) unsigned short wcomb_lds[16][LSTR];  // 65.8 KB
  __shared__ __align__(16) unsigned short mixed_lds[5][LSTR];   // 20.6 KB, row4 = zeros
  __shared__ __align__(16) float spbuf[16][4];
  __shared__ __align__(16) float bcomb_lds[16];
  __shared__ __align__(16) unsigned short nlbuf[4][8];

  const int lane = threadIdx.x, bid = blockIdx.x;
  const int I0 = bid * 8;
  const int col = lane & 15;            // MFMA row/col index
  const int krow = (lane >> 4) << 3;    // MFMA k-subgroup offset

  // ---- prologue: stage Wcomb slice (u rows I0.., g rows 2048+I0..) ----
  for (int c = lane; c < 4096; c += 64) {
    int r = c >> 8, kp = (c & 255) << 3;
    int gj = (r < 8) ? (I0 + r) : (2048 + I0 + r - 8);
    *(uint4*)&wcomb_lds[r][kp] = *(const uint4*)&wcombg[((size_t)gj << 11) + kp];
  }
  // zero pad row (B-fragment source for unused MFMA cols 4..15)
  for (int c = lane; c < 256; c += 64) {
    uint4 z; z.x = 0; z.y = 0; z.z = 0; z.w = 0;
    ((uint4*)&mixed_lds[4][0])[c] = z;
  }
  if (lane < 16) bcomb_lds[lane] = bcombg[(lane < 8) ? (I0 + lane) : (2048 + I0 + lane - 8)];

  // ---- prologue: t=0 tokens + sp0 into registers (lanes 0..31) ----
  unsigned short rtu = 0, rtg = 0, rtv = 0;
  float su0 = 0.f, sg0 = 0.f;
  if (lane < 32) {
    const int i = lane & 7, bb = lane >> 3;
    size_t base = (size_t)(bb * 2048) * 6144 + I0 + i;
    rtu = projg[base];
    rtg = projg[base + 2048];
    rtv = projg[base + 4096];
    su0 = sp0g[bb * 4096 + I0 + i];
    sg0 = sp0g[bb * 4096 + 2048 + I0 + i];
  }
  WAIT_LGKM0();

  const unsigned short* arow = &wcomb_lds[col][0];
  const unsigned short* brow = &mixed_lds[(col < 4) ? col : 4][0];

#pragma unroll 1
  for (int t = 0; t < S_LEN; ++t) {
    float su = su0, sg = sg0;
    if (t > 0) {
      // ---- poll-stage region t-1: 32 x 8B agent atomic loads per lane ----
      // chunk c: 8B index g2 = lane + c*64; row = c>>3 (const), col8 = lane+(c&7)*64
      const unsigned long long* src =
          (const unsigned long long*)(mixedg + ((size_t)(t - 1) << 13));
      unsigned miss = 0u;
#pragma unroll
      for (int c = 0; c < 32; ++c) {
        unsigned long long v = __hip_atomic_load(&src[lane + (c << 6)],
                                                 __ATOMIC_RELAXED, __HIP_MEMORY_SCOPE_AGENT);
        if ((unsigned)v == MAGIC) {
          miss |= 1u << c;
        } else {
          *(unsigned long long*)&mixed_lds[c >> 3][(lane + ((c & 7) << 6)) << 2] = v;
        }
      }
      while (miss) {  // straggler chunks (rare)
        int c = __builtin_ctz(miss);
        unsigned long long v = __hip_atomic_load(&src[lane + (c << 6)],
                                                 __ATOMIC_RELAXED, __HIP_MEMORY_SCOPE_AGENT);
        if ((unsigned)v != MAGIC) {
          *(unsigned long long*)&mixed_lds[c >> 3][(lane + ((c & 7) << 6)) << 2] = v;
          miss &= miss - 1;
        } else {
          __builtin_amdgcn_s_sleep(1);
        }
      }
      WAIT_LGKM0();  // LDS writes complete (same wave)

      // ---- MFMA dot: D[j, bb] = sum_k W[j,k] * mx[bb,k] ----
      f32x4 acc = (f32x4)0.f;
#pragma unroll 4
      for (int k0 = 0; k0 < 2048; k0 += 32) {
        bf16x8 a = *(const bf16x8*)&arow[k0 + krow];
        bf16x8 b = *(const bf16x8*)&brow[k0 + krow];
        acc = __builtin_amdgcn_mfma_f32_16x16x32_bf16(a, b, acc, 0, 0, 0);
      }
      if (col < 4) {
#pragma unroll
        for (int r = 0; r < 4; ++r) spbuf[((lane >> 4) << 2) + r][col] = acc[r];
      }
      WAIT_LGKM0();  // spbuf visible within wave
      if (lane < 32) {
        const int i = lane & 7, bb = lane >> 3;
        su = spbuf[i][bb] + bcomb_lds[i];
        sg = spbuf[8 + i][bb] + bcomb_lds[8 + i];
      }
    }

    // ---- nonlinearity (lanes 0..31), tokens from registers ----
    if (lane < 32) {
      float tu = b2f(rtu), tg = b2f(rtg), tv = b2f(rtv);
      float cand = tanhf(tu + su);
      float gate = 1.0f / (1.0f + expf(-(tg + sg)));
      float mix = gate * cand + (1.0f - gate) * tanhf(tv);
      nlbuf[lane >> 3][lane & 7] = f2bf(mix);
    }
    WAIT_LGKM0();  // nlbuf visible within wave

    // ---- publish slice: 8 x 8B RETURNING atomic swaps (atomic at LLC) ----
    if (lane < 8) {
      const int bb = lane >> 1, half = lane & 1;
      unsigned long long val = *(const unsigned long long*)&nlbuf[bb][half * 4];
      unsigned long long* dst =
          (unsigned long long*)(mixedg + ((size_t)t * 4 + bb) * 2048 + I0) + half;
      unsigned long long old = __hip_atomic_exchange(dst, val,
                                                     __ATOMIC_RELAXED, __HIP_MEMORY_SCOPE_AGENT);
      asm volatile("" :: "v"((unsigned)old));  // keep returning form live (sc0)
    }

    // ---- token prefetch for step t+1 (hidden under next poll-stage) ----
    if (t < S_LEN - 1 && lane < 32) {
      const int i = lane & 7, bb = lane >> 3;
      size_t base = (size_t)(bb * 2048 + t + 1) * 6144 + I0 + i;
      rtu = projg[base];
      rtg = projg[base + 2048];
      rtv = projg[base + 4096];
    }
  }
}

extern "C" void kernel_launch(void* const* d_in, const int* in_sizes, int n_in,
                              void* d_out, int out_size, void* d_ws, size_t ws_size,
                              hipStream_t stream) {
  (void)in_sizes; (void)n_in; (void)out_size; (void)ws_size;
  const float* hidden = (const float*)d_in[0];
  const float* state0 = (const float*)d_in[1];
  const float* w_in   = (const float*)d_in[2];
  const float* b_in   = (const float*)d_in[3];
  const float* w_sp   = (const float*)d_in[4];
  const float* b_sp   = (const float*)d_in[5];
  const float* w_out  = (const float*)d_in[6];
  const float* b_out  = (const float*)d_in[7];
  const float* w_up   = (const float*)d_in[8];
  const float* b_up   = (const float*)d_in[9];
  float* out = (float*)d_out;
  char* ws = (char*)d_ws;

  size_t o = 0;
  auto take = [&](size_t b) { size_t p = o; o += (b + 255) & ~(size_t)255; return p; };
  unsigned* cntp         = (unsigned*)(ws + take(256 * 4));  // unused this round
  float* sp0p            = (float*)(ws + take((size_t)4 * 4096 * 4));
  float* bcombp          = (float*)(ws + take((size_t)4096 * 4));
  unsigned short* hbf    = (unsigned short*)(ws + take((size_t)8192 * 1024 * 2));
  unsigned short* winbf  = (unsigned short*)(ws + take((size_t)6144 * 1024 * 2));
  unsigned short* wspbf  = (unsigned short*)(ws + take((size_t)4096 * 512 * 2));
  unsigned short* wupTbf = (unsigned short*)(ws + take((size_t)2048 * 512 * 2));
  unsigned short* woutbf = (unsigned short*)(ws + take((size_t)1024 * 2048 * 2));
  unsigned short* wcombbf= (unsigned short*)(ws + take((size_t)4096 * 2048 * 2));
  unsigned short* projbf = (unsigned short*)(ws + take((size_t)8192 * 6144 * 2));
  unsigned short* mixbf  = (unsigned short*)(ws + take((size_t)8192 * 2048 * 2));
  (void)cntp;

  // sentinel-fill mixedg: byte 0x7F -> dword 0x7F7F7F7F (bf16 0x7F7F ~ 3.4e38,
  // impossible for mixed values in (-1,1))
  hipMemsetAsync(mixbf, 0x7F, (size_t)8192 * 2048 * 2, stream);

  conv_f32_bf16<<<4096, 256, 0, stream>>>(hidden, hbf, 1048576);
  conv_f32_bf16<<<3072, 256, 0, stream>>>(w_in, winbf, 786432);
  conv_f32_bf16<<<1024, 256, 0, stream>>>(w_sp, wspbf, 262144);
  conv_f32_bf16<<<1024, 256, 0, stream>>>(w_out, woutbf, 262144);
  transpose_wup<<<4096, 256, 0, stream>>>(w_up, wupTbf);

  // projected = hidden @ in_proj_w^T + b_in   [8192, 6144] bf16
  gemm_bt<0><<<dim3(64, 48), 256, 0, stream>>>(hbf, winbf, projbf, nullptr, b_in, 8192, 6144, 1024);
  // Wcomb = Wsp @ Wup   [4096, 2048] bf16  (B = Wup^T as [2048,512])
  gemm_bt<1><<<dim3(32, 16), 256, 0, stream>>>(wspbf, wupTbf, wcombbf, nullptr, nullptr, 4096, 2048, 512);

  bcomb_kernel<<<1024, 256, 0, stream>>>(w_sp, b_sp, b_up, bcombp);
  sp0_kernel<<<1024, 256, 0, stream>>>(w_sp, b_sp, state0, sp0p);

  {
    const unsigned short* a0 = wcombbf;
    const float* a1 = bcombp;
    const float* a2 = sp0p;
    const unsigned short* a3 = projbf;
    unsigned short* a4 = mixbf;
    void* args[] = {&a0, &a1, &a2, &a3, &a4};
    hipLaunchCooperativeKernel((const void*)scan_kernel, dim3(NBLK), dim3(64), args, 0, stream);
  }

  // out = mixed @ out_proj_w^T + b_out  -> fp32, remapped to [B,S,D]
  gemm_bt<2><<<dim3(64, 8), 256, 0, stream>>>(mixbf, woutbf, nullptr, out, b_out, 8192, 1024, 2048);
  final_state_kernel<<<128, 256, 0, stream>>>(w_up, b_up, mixbf, out + (size_t)8192 * 1024);
}

// Round 11
// 17296.829 us; speedup vs baseline: 1.3109x; 1.3109x over previous
//
#include <hip/hip_runtime.h>
#include <hip/hip_bf16.h>

// Problem: B=4, S=2048, D=1024, INNER=2048, STATE=512.
// out = out_proj(scan(in_proj(hidden)));  scan folded via Wcomb = Wsp @ Wup.
// Round 11 = round-10 sentinel protocol + HYBRID staging:
//   first pass: plain 16B loads (fast, coalesced), sentinel-check both 8B halves;
//   stragglers: 8B agent atomic loads (bypass stale L2);
//   publish: fire-and-forget 8B agent atomic stores (no drain/counter/flag).
// Safe because every mixedg address transitions MAGIC->final exactly once:
// stale caches can only show MAGIC, never wrong data.

#define S_LEN 2048
#define NBATCH 4
#define NBLK 256
#define LSTR 2056      // padded LDS row stride in bf16 (4112 B, 16B-aligned)
#define MAGIC 0x7F7F7F7Fu

typedef __attribute__((ext_vector_type(4))) float f32x4;
typedef __attribute__((ext_vector_type(8))) short bf16x8;

__device__ __forceinline__ unsigned short f2bf(float f) {
  unsigned u = __builtin_bit_cast(unsigned, f);
  u += 0x7FFFu + ((u >> 16) & 1u);
  return (unsigned short)(u >> 16);
}
__device__ __forceinline__ float b2f(unsigned short s) { return __builtin_bit_cast(float, (unsigned)s << 16); }

__device__ __forceinline__ float wave_sum64(float v) {
#pragma unroll
  for (int m = 32; m >= 1; m >>= 1) v += __shfl_xor(v, m, 64);
  return v;
}

#define WAIT_LGKM0() asm volatile("s_waitcnt lgkmcnt(0)" ::: "memory")

// ---------------- fp32 -> bf16 convert (8 elems/thread) ----------------
__global__ void conv_f32_bf16(const float* __restrict__ in, unsigned short* __restrict__ out, int n8) {
  int g = blockIdx.x * 256 + threadIdx.x;
  if (g >= n8) return;
  const float4* p = (const float4*)in + 2 * (size_t)g;
  float4 a = p[0], b = p[1];
  uint4 o;
  o.x = (unsigned)f2bf(a.x) | ((unsigned)f2bf(a.y) << 16);
  o.y = (unsigned)f2bf(a.z) | ((unsigned)f2bf(a.w) << 16);
  o.z = (unsigned)f2bf(b.x) | ((unsigned)f2bf(b.y) << 16);
  o.w = (unsigned)f2bf(b.z) | ((unsigned)f2bf(b.w) << 16);
  ((uint4*)out)[g] = o;
}

// ---------------- Wup [512][2048] -> WupT bf16 [2048][512] ----------------
__global__ void transpose_wup(const float* __restrict__ in, unsigned short* __restrict__ out) {
  int g = blockIdx.x * 256 + threadIdx.x; // over 2048*512
  int i = g >> 9, k = g & 511;
  out[g] = f2bf(in[(size_t)k * 2048 + i]);
}

// ---------------- b_comb[j] = b_sp[j] + sum_k Wsp[j,k]*b_up[k] ----------------
__global__ void bcomb_kernel(const float* __restrict__ wsp, const float* __restrict__ bsp,
                             const float* __restrict__ bup, float* __restrict__ bcomb) {
  int wv = (blockIdx.x * 256 + threadIdx.x) >> 6;
  int lane = threadIdx.x & 63;
  if (wv >= 4096) return;
  float s = 0.f;
  for (int k = lane; k < 512; k += 64) s += wsp[(size_t)wv * 512 + k] * bup[k];
  s = wave_sum64(s);
  if (lane == 0) bcomb[wv] = s + bsp[wv];
}

// ---------------- sp0[b][j] = b_sp[j] + sum_k state0[b,k]*Wsp[j,k] ----------------
__global__ void sp0_kernel(const float* __restrict__ wsp, const float* __restrict__ bsp,
                           const float* __restrict__ state0, float* __restrict__ sp0) {
  int wv = (blockIdx.x * 256 + threadIdx.x) >> 6;
  int lane = threadIdx.x & 63;
  if (wv >= 4096) return;
  float acc[NBATCH] = {0.f, 0.f, 0.f, 0.f};
  for (int k = lane; k < 512; k += 64) {
    float w = wsp[(size_t)wv * 512 + k];
#pragma unroll
    for (int bb = 0; bb < NBATCH; ++bb) acc[bb] += state0[bb * 512 + k] * w;
  }
#pragma unroll
  for (int bb = 0; bb < NBATCH; ++bb) acc[bb] = wave_sum64(acc[bb]);
  if (lane == 0) {
    float b = bsp[wv];
#pragma unroll
    for (int bb = 0; bb < NBATCH; ++bb) sp0[bb * 4096 + wv] = acc[bb] + b;
  }
}

// ---------------- final_state[b][j] = b_up[j] + sum_i mixed[2047,b,i]*Wup[j,i] ----------------
__global__ void final_state_kernel(const float* __restrict__ wup, const float* __restrict__ bup,
                                   const unsigned short* __restrict__ mixedg, float* __restrict__ dst) {
  int wv = (blockIdx.x * 256 + threadIdx.x) >> 6;
  int lane = threadIdx.x & 63;
  if (wv >= 512) return;
  float acc[NBATCH] = {0.f, 0.f, 0.f, 0.f};
  for (int i = lane; i < 2048; i += 64) {
    float w = wup[(size_t)wv * 2048 + i];
#pragma unroll
    for (int bb = 0; bb < NBATCH; ++bb)
      acc[bb] += b2f(mixedg[((size_t)2047 * 4 + bb) * 2048 + i]) * w;
  }
#pragma unroll
  for (int bb = 0; bb < NBATCH; ++bb) acc[bb] = wave_sum64(acc[bb]);
  if (lane == 0) {
    float b = bup[wv];
#pragma unroll
    for (int bb = 0; bb < NBATCH; ++bb) dst[bb * 512 + wv] = acc[bb] + b;
  }
}

// ---------------- bf16 BT-GEMM: C[M,N] = A[M,K] @ B[N,K]^T (+bias) ----------------
// MODE 0: bf16 out + bias; MODE 1: bf16 out, no bias; MODE 2: fp32 out, bias,
// row remap m=s*4+b -> out[b][s][n] (S=2048, N=1024 hardcoded for out_proj).
template <int MODE>
__global__ __launch_bounds__(256) void gemm_bt(
    const unsigned short* __restrict__ A, const unsigned short* __restrict__ B,
    unsigned short* __restrict__ Cbf, float* __restrict__ Cf32,
    const float* __restrict__ bias, int M, int N, int K) {
  const int tm = blockIdx.x * 128, tn = blockIdx.y * 128;
  __shared__ __align__(16) unsigned short At[128][72];
  __shared__ __align__(16) unsigned short Bt[128][72];
  const int tid = threadIdx.x, lane = tid & 63, w = tid >> 6;
  const int wm = (w >> 1) * 64, wn = (w & 1) * 64;
  f32x4 acc[4][4];
#pragma unroll
  for (int a = 0; a < 4; ++a)
#pragma unroll
    for (int b = 0; b < 4; ++b) acc[a][b] = (f32x4)0.f;

  for (int k0 = 0; k0 < K; k0 += 64) {
#pragma unroll
    for (int it = 0; it < 4; ++it) {
      int c = tid + it * 256;
      int r = c >> 3, kp = (c & 7) * 8;
      *(uint4*)&At[r][kp] = *(const uint4*)&A[(size_t)(tm + r) * K + k0 + kp];
      *(uint4*)&Bt[r][kp] = *(const uint4*)&B[(size_t)(tn + r) * K + k0 + kp];
    }
    __syncthreads();
#pragma unroll
    for (int kk = 0; kk < 2; ++kk) {
      bf16x8 af[4], bfr[4];
#pragma unroll
      for (int fm = 0; fm < 4; ++fm)
        af[fm] = *(const bf16x8*)&At[wm + fm * 16 + (lane & 15)][(kk << 5) + ((lane >> 4) << 3)];
#pragma unroll
      for (int fn = 0; fn < 4; ++fn)
        bfr[fn] = *(const bf16x8*)&Bt[wn + fn * 16 + (lane & 15)][(kk << 5) + ((lane >> 4) << 3)];
#pragma unroll
      for (int fm = 0; fm < 4; ++fm)
#pragma unroll
        for (int fn = 0; fn < 4; ++fn)
          acc[fm][fn] = __builtin_amdgcn_mfma_f32_16x16x32_bf16(af[fm], bfr[fn], acc[fm][fn], 0, 0, 0);
    }
    __syncthreads();
  }
  // epilogue
  float bv[4];
#pragma unroll
  for (int fn = 0; fn < 4; ++fn) {
    if constexpr (MODE != 1) bv[fn] = bias[tn + wn + fn * 16 + (lane & 15)];
    else bv[fn] = 0.f;
  }
#pragma unroll
  for (int fm = 0; fm < 4; ++fm)
#pragma unroll
    for (int fn = 0; fn < 4; ++fn)
#pragma unroll
      for (int r = 0; r < 4; ++r) {
        int row = tm + wm + fm * 16 + ((lane >> 4) << 2) + r;
        int col = tn + wn + fn * 16 + (lane & 15);
        float v = acc[fm][fn][r] + bv[fn];
        if constexpr (MODE == 2) {
          Cf32[(size_t)(((row & 3) << 11) + (row >> 2)) * 1024 + col] = v;
        } else {
          Cbf[(size_t)row * N + col] = f2bf(v);
        }
      }
}

// ---------------- persistent scan kernel (single wave per block) ----------------
// 256 blocks x 64 threads, 1 block/CU. Block b owns INNER slice [8b, 8b+8).
// Sentinel protocol + hybrid staging. Per step:
//   stage region t-1: plain 16B loads w/ sentinel check, atomic retry stragglers;
//   MFMA dot (padded LDS, r9-identical); nonlinearity;
//   publish slice: 8 x 8B fire-and-forget agent atomic stores.
__global__ __launch_bounds__(64, 1) void scan_kernel(
    const unsigned short* __restrict__ wcombg,  // [4096][2048] bf16
    const float* __restrict__ bcombg,           // [4096]
    const float* __restrict__ sp0g,             // [4][4096]
    const unsigned short* __restrict__ projg,   // [8192][6144] bf16, m=b*2048+s
    unsigned short* __restrict__ mixedg)        // [2048][4][2048] bf16, MAGIC-filled
{
  __shared__ __align__(16) unsigned short wcomb_lds[16][LSTR];  // 65.8 KB
  __shared__ __align__(16) unsigned short mixed_lds[5][LSTR];   // 20.6 KB, row4 = zeros
  __shared__ __align__(16) float spbuf[16][4];
  __shared__ __align__(16) float bcomb_lds[16];
  __shared__ __align__(16) unsigned short nlbuf[4][8];

  const int lane = threadIdx.x, bid = blockIdx.x;
  const int I0 = bid * 8;
  const int col = lane & 15;            // MFMA row/col index
  const int krow = (lane >> 4) << 3;    // MFMA k-subgroup offset

  // ---- prologue: stage Wcomb slice (u rows I0.., g rows 2048+I0..) ----
  for (int c = lane; c < 4096; c += 64) {
    int r = c >> 8, kp = (c & 255) << 3;
    int gj = (r < 8) ? (I0 + r) : (2048 + I0 + r - 8);
    *(uint4*)&wcomb_lds[r][kp] = *(const uint4*)&wcombg[((size_t)gj << 11) + kp];
  }
  // zero pad row (B-fragment source for unused MFMA cols 4..15)
  for (int c = lane; c < 256; c += 64) {
    uint4 z; z.x = 0; z.y = 0; z.z = 0; z.w = 0;
    ((uint4*)&mixed_lds[4][0])[c] = z;
  }
  if (lane < 16) bcomb_lds[lane] = bcombg[(lane < 8) ? (I0 + lane) : (2048 + I0 + lane - 8)];

  // ---- prologue: t=0 tokens + sp0 into registers (lanes 0..31) ----
  unsigned short rtu = 0, rtg = 0, rtv = 0;
  float su0 = 0.f, sg0 = 0.f;
  if (lane < 32) {
    const int i = lane & 7, bb = lane >> 3;
    size_t base = (size_t)(bb * 2048) * 6144 + I0 + i;
    rtu = projg[base];
    rtg = projg[base + 2048];
    rtv = projg[base + 4096];
    su0 = sp0g[bb * 4096 + I0 + i];
    sg0 = sp0g[bb * 4096 + 2048 + I0 + i];
  }
  WAIT_LGKM0();

  const unsigned short* arow = &wcomb_lds[col][0];
  const unsigned short* brow = &mixed_lds[(col < 4) ? col : 4][0];

#pragma unroll 1
  for (int t = 0; t < S_LEN; ++t) {
    float su = su0, sg = sg0;
    if (t > 0) {
      // ---- hybrid stage of region t-1 ----
      const uint4* src = (const uint4*)(mixedg + ((size_t)(t - 1) << 13));
      const unsigned long long* src64 = (const unsigned long long*)src;
      unsigned miss = 0u;
#pragma unroll
      for (int c = 0; c < 16; ++c) {
        int u = lane + (c << 6);               // uint4 index 0..1023
        uint4 v = src[u];                      // plain coalesced 16B load
        // each 8B half was written atomically; low dword marks validity
        if (v.x == MAGIC || v.z == MAGIC) {
          miss |= 1u << c;
        } else {
          *(uint4*)&mixed_lds[u >> 8][(u & 255) << 3] = v;
        }
      }
      while (miss) {  // stragglers: atomic loads bypass (possibly stale) L2
        int c = __builtin_ctz(miss);
        int u = lane + (c << 6);
        unsigned long long a = __hip_atomic_load(&src64[2 * u],
                                                 __ATOMIC_RELAXED, __HIP_MEMORY_SCOPE_AGENT);
        unsigned long long b = __hip_atomic_load(&src64[2 * u + 1],
                                                 __ATOMIC_RELAXED, __HIP_MEMORY_SCOPE_AGENT);
        if ((unsigned)a != MAGIC && (unsigned)b != MAGIC) {
          *(unsigned long long*)&mixed_lds[u >> 8][(u & 255) << 3] = a;
          *(unsigned long long*)&mixed_lds[u >> 8][((u & 255) << 3) + 4] = b;
          miss &= miss - 1;
        } else {
          __builtin_amdgcn_s_sleep(1);
        }
      }
      WAIT_LGKM0();  // LDS writes complete (same wave)

      // ---- MFMA dot: D[j, bb] = sum_k W[j,k] * mx[bb,k] ----
      f32x4 acc = (f32x4)0.f;
#pragma unroll 4
      for (int k0 = 0; k0 < 2048; k0 += 32) {
        bf16x8 a = *(const bf16x8*)&arow[k0 + krow];
        bf16x8 b = *(const bf16x8*)&brow[k0 + krow];
        acc = __builtin_amdgcn_mfma_f32_16x16x32_bf16(a, b, acc, 0, 0, 0);
      }
      if (col < 4) {
#pragma unroll
        for (int r = 0; r < 4; ++r) spbuf[((lane >> 4) << 2) + r][col] = acc[r];
      }
      WAIT_LGKM0();  // spbuf visible within wave
      if (lane < 32) {
        const int i = lane & 7, bb = lane >> 3;
        su = spbuf[i][bb] + bcomb_lds[i];
        sg = spbuf[8 + i][bb] + bcomb_lds[8 + i];
      }
    }

    // ---- nonlinearity (lanes 0..31), tokens from registers ----
    if (lane < 32) {
      float tu = b2f(rtu), tg = b2f(rtg), tv = b2f(rtv);
      float cand = tanhf(tu + su);
      float gate = 1.0f / (1.0f + expf(-(tg + sg)));
      float mix = gate * cand + (1.0f - gate) * tanhf(tv);
      nlbuf[lane >> 3][lane & 7] = f2bf(mix);
    }
    WAIT_LGKM0();  // nlbuf visible within wave

    // ---- publish slice: 8 x 8B fire-and-forget agent atomic stores ----
    if (lane < 8) {
      const int bb = lane >> 1, half = lane & 1;
      unsigned long long val = *(const unsigned long long*)&nlbuf[bb][half * 4];
      unsigned long long* dst =
          (unsigned long long*)(mixedg + ((size_t)t * 4 + bb) * 2048 + I0) + half;
      __hip_atomic_store(dst, val, __ATOMIC_RELAXED, __HIP_MEMORY_SCOPE_AGENT);
    }

    // ---- token prefetch for step t+1 (hidden under next stage) ----
    if (t < S_LEN - 1 && lane < 32) {
      const int i = lane & 7, bb = lane >> 3;
      size_t base = (size_t)(bb * 2048 + t + 1) * 6144 + I0 + i;
      rtu = projg[base];
      rtg = projg[base + 2048];
      rtv = projg[base + 4096];
    }
  }
}

extern "C" void kernel_launch(void* const* d_in, const int* in_sizes, int n_in,
                              void* d_out, int out_size, void* d_ws, size_t ws_size,
                              hipStream_t stream) {
  (void)in_sizes; (void)n_in; (void)out_size; (void)ws_size;
  const float* hidden = (const float*)d_in[0];
  const float* state0 = (const float*)d_in[1];
  const float* w_in   = (const float*)d_in[2];
  const float* b_in   = (const float*)d_in[3];
  const float* w_sp   = (const float*)d_in[4];
  const float* b_sp   = (const float*)d_in[5];
  const float* w_out  = (const float*)d_in[6];
  const float* b_out  = (const float*)d_in[7];
  const float* w_up   = (const float*)d_in[8];
  const float* b_up   = (const float*)d_in[9];
  float* out = (float*)d_out;
  char* ws = (char*)d_ws;

  size_t o = 0;
  auto take = [&](size_t b) { size_t p = o; o += (b + 255) & ~(size_t)255; return p; };
  unsigned* cntp         = (unsigned*)(ws + take(256 * 4));  // unused this round
  float* sp0p            = (float*)(ws + take((size_t)4 * 4096 * 4));
  float* bcombp          = (float*)(ws + take((size_t)4096 * 4));
  unsigned short* hbf    = (unsigned short*)(ws + take((size_t)8192 * 1024 * 2));
  unsigned short* winbf  = (unsigned short*)(ws + take((size_t)6144 * 1024 * 2));
  unsigned short* wspbf  = (unsigned short*)(ws + take((size_t)4096 * 512 * 2));
  unsigned short* wupTbf = (unsigned short*)(ws + take((size_t)2048 * 512 * 2));
  unsigned short* woutbf = (unsigned short*)(ws + take((size_t)1024 * 2048 * 2));
  unsigned short* wcombbf= (unsigned short*)(ws + take((size_t)4096 * 2048 * 2));
  unsigned short* projbf = (unsigned short*)(ws + take((size_t)8192 * 6144 * 2));
  unsigned short* mixbf  = (unsigned short*)(ws + take((size_t)8192 * 2048 * 2));
  (void)cntp;

  // sentinel-fill mixedg: byte 0x7F -> dword 0x7F7F7F7F (impossible bf16 pair
  // for mixed values in (-1,1))
  hipMemsetAsync(mixbf, 0x7F, (size_t)8192 * 2048 * 2, stream);

  conv_f32_bf16<<<4096, 256, 0, stream>>>(hidden, hbf, 1048576);
  conv_f32_bf16<<<3072, 256, 0, stream>>>(w_in, winbf, 786432);
  conv_f32_bf16<<<1024, 256, 0, stream>>>(w_sp, wspbf, 262144);
  conv_f32_bf16<<<1024, 256, 0, stream>>>(w_out, woutbf, 262144);
  transpose_wup<<<4096, 256, 0, stream>>>(w_up, wupTbf);

  // projected = hidden @ in_proj_w^T + b_in   [8192, 6144] bf16
  gemm_bt<0><<<dim3(64, 48), 256, 0, stream>>>(hbf, winbf, projbf, nullptr, b_in, 8192, 6144, 1024);
  // Wcomb = Wsp @ Wup   [4096, 2048] bf16  (B = Wup^T as [2048,512])
  gemm_bt<1><<<dim3(32, 16), 256, 0, stream>>>(wspbf, wupTbf, wcombbf, nullptr, nullptr, 4096, 2048, 512);

  bcomb_kernel<<<1024, 256, 0, stream>>>(w_sp, b_sp, b_up, bcombp);
  sp0_kernel<<<1024, 256, 0, stream>>>(w_sp, b_sp, state0, sp0p);

  {
    const unsigned short* a0 = wcombbf;
    const float* a1 = bcombp;
    const float* a2 = sp0p;
    const unsigned short* a3 = projbf;
    unsigned short* a4 = mixbf;
    void* args[] = {&a0, &a1, &a2, &a3, &a4};
    hipLaunchCooperativeKernel((const void*)scan_kernel, dim3(NBLK), dim3(64), args, 0, stream);
  }

  // out = mixed @ out_proj_w^T + b_out  -> fp32, remapped to [B,S,D]
  gemm_bt<2><<<dim3(64, 8), 256, 0, stream>>>(mixbf, woutbf, nullptr, out, b_out, 8192, 1024, 2048);
  final_state_kernel<<<128, 256, 0, stream>>>(w_up, b_up, mixbf, out + (size_t)8192 * 1024);
}

// Round 12
// 9148.901 us; speedup vs baseline: 2.4785x; 1.8906x over previous
//
#include <hip/hip_runtime.h>
#include <hip/hip_bf16.h>

// Problem: B=4, S=2048, D=1024, INNER=2048, STATE=512.
// out = out_proj(scan(in_proj(hidden)));  scan folded via Wcomb = Wsp @ Wup.
// Round 12 = round-9 (PASS, 13.9ms) + ONE change: the cumulative counter is
// spread over 8 lines 128B apart (cnt[(bid&7)<<5]); poll reads all 8 with one
// wave-level atomic-load (lanes 0-7) + shuffle-sum. Tests the theory that 256
// near-simultaneous atomicAdds on ONE address serialize ~1-2.5us at the LLC.
// Everything else byte-identical to round 9.

#define S_LEN 2048
#define NBATCH 4
#define NBLK 256
#define LSTR 2056  // padded LDS row stride in bf16 (4112 B, 16B-aligned)

typedef __attribute__((ext_vector_type(4))) float f32x4;
typedef __attribute__((ext_vector_type(8))) short bf16x8;

__device__ __forceinline__ unsigned short f2bf(float f) {
  unsigned u = __builtin_bit_cast(unsigned, f);
  u += 0x7FFFu + ((u >> 16) & 1u);
  return (unsigned short)(u >> 16);
}
__device__ __forceinline__ float b2f(unsigned short s) { return __builtin_bit_cast(float, (unsigned)s << 16); }

__device__ __forceinline__ float wave_sum64(float v) {
#pragma unroll
  for (int m = 32; m >= 1; m >>= 1) v += __shfl_xor(v, m, 64);
  return v;
}

#define WAIT_VM0()   asm volatile("s_waitcnt vmcnt(0)" ::: "memory")
#define WAIT_LGKM0() asm volatile("s_waitcnt lgkmcnt(0)" ::: "memory")

// ---------------- fp32 -> bf16 convert (8 elems/thread) ----------------
__global__ void conv_f32_bf16(const float* __restrict__ in, unsigned short* __restrict__ out, int n8) {
  int g = blockIdx.x * 256 + threadIdx.x;
  if (g >= n8) return;
  const float4* p = (const float4*)in + 2 * (size_t)g;
  float4 a = p[0], b = p[1];
  uint4 o;
  o.x = (unsigned)f2bf(a.x) | ((unsigned)f2bf(a.y) << 16);
  o.y = (unsigned)f2bf(a.z) | ((unsigned)f2bf(a.w) << 16);
  o.z = (unsigned)f2bf(b.x) | ((unsigned)f2bf(b.y) << 16);
  o.w = (unsigned)f2bf(b.z) | ((unsigned)f2bf(b.w) << 16);
  ((uint4*)out)[g] = o;
}

// ---------------- Wup [512][2048] -> WupT bf16 [2048][512] ----------------
__global__ void transpose_wup(const float* __restrict__ in, unsigned short* __restrict__ out) {
  int g = blockIdx.x * 256 + threadIdx.x; // over 2048*512
  int i = g >> 9, k = g & 511;
  out[g] = f2bf(in[(size_t)k * 2048 + i]);
}

// ---------------- b_comb[j] = b_sp[j] + sum_k Wsp[j,k]*b_up[k] ----------------
__global__ void bcomb_kernel(const float* __restrict__ wsp, const float* __restrict__ bsp,
                             const float* __restrict__ bup, float* __restrict__ bcomb) {
  int wv = (blockIdx.x * 256 + threadIdx.x) >> 6;
  int lane = threadIdx.x & 63;
  if (wv >= 4096) return;
  float s = 0.f;
  for (int k = lane; k < 512; k += 64) s += wsp[(size_t)wv * 512 + k] * bup[k];
  s = wave_sum64(s);
  if (lane == 0) bcomb[wv] = s + bsp[wv];
}

// ---------------- sp0[b][j] = b_sp[j] + sum_k state0[b,k]*Wsp[j,k] ----------------
__global__ void sp0_kernel(const float* __restrict__ wsp, const float* __restrict__ bsp,
                           const float* __restrict__ state0, float* __restrict__ sp0) {
  int wv = (blockIdx.x * 256 + threadIdx.x) >> 6;
  int lane = threadIdx.x & 63;
  if (wv >= 4096) return;
  float acc[NBATCH] = {0.f, 0.f, 0.f, 0.f};
  for (int k = lane; k < 512; k += 64) {
    float w = wsp[(size_t)wv * 512 + k];
#pragma unroll
    for (int bb = 0; bb < NBATCH; ++bb) acc[bb] += state0[bb * 512 + k] * w;
  }
#pragma unroll
  for (int bb = 0; bb < NBATCH; ++bb) acc[bb] = wave_sum64(acc[bb]);
  if (lane == 0) {
    float b = bsp[wv];
#pragma unroll
    for (int bb = 0; bb < NBATCH; ++bb) sp0[bb * 4096 + wv] = acc[bb] + b;
  }
}

// ---------------- final_state[b][j] = b_up[j] + sum_i mixed[2047,b,i]*Wup[j,i] ----------------
__global__ void final_state_kernel(const float* __restrict__ wup, const float* __restrict__ bup,
                                   const unsigned short* __restrict__ mixedg, float* __restrict__ dst) {
  int wv = (blockIdx.x * 256 + threadIdx.x) >> 6;
  int lane = threadIdx.x & 63;
  if (wv >= 512) return;
  float acc[NBATCH] = {0.f, 0.f, 0.f, 0.f};
  for (int i = lane; i < 2048; i += 64) {
    float w = wup[(size_t)wv * 2048 + i];
#pragma unroll
    for (int bb = 0; bb < NBATCH; ++bb)
      acc[bb] += b2f(mixedg[((size_t)2047 * 4 + bb) * 2048 + i]) * w;
  }
#pragma unroll
  for (int bb = 0; bb < NBATCH; ++bb) acc[bb] = wave_sum64(acc[bb]);
  if (lane == 0) {
    float b = bup[wv];
#pragma unroll
    for (int bb = 0; bb < NBATCH; ++bb) dst[bb * 512 + wv] = acc[bb] + b;
  }
}

// ---------------- bf16 BT-GEMM: C[M,N] = A[M,K] @ B[N,K]^T (+bias) ----------------
// MODE 0: bf16 out + bias; MODE 1: bf16 out, no bias; MODE 2: fp32 out, bias,
// row remap m=s*4+b -> out[b][s][n] (S=2048, N=1024 hardcoded for out_proj).
template <int MODE>
__global__ __launch_bounds__(256) void gemm_bt(
    const unsigned short* __restrict__ A, const unsigned short* __restrict__ B,
    unsigned short* __restrict__ Cbf, float* __restrict__ Cf32,
    const float* __restrict__ bias, int M, int N, int K) {
  const int tm = blockIdx.x * 128, tn = blockIdx.y * 128;
  __shared__ __align__(16) unsigned short At[128][72];
  __shared__ __align__(16) unsigned short Bt[128][72];
  const int tid = threadIdx.x, lane = tid & 63, w = tid >> 6;
  const int wm = (w >> 1) * 64, wn = (w & 1) * 64;
  f32x4 acc[4][4];
#pragma unroll
  for (int a = 0; a < 4; ++a)
#pragma unroll
    for (int b = 0; b < 4; ++b) acc[a][b] = (f32x4)0.f;

  for (int k0 = 0; k0 < K; k0 += 64) {
#pragma unroll
    for (int it = 0; it < 4; ++it) {
      int c = tid + it * 256;
      int r = c >> 3, kp = (c & 7) * 8;
      *(uint4*)&At[r][kp] = *(const uint4*)&A[(size_t)(tm + r) * K + k0 + kp];
      *(uint4*)&Bt[r][kp] = *(const uint4*)&B[(size_t)(tn + r) * K + k0 + kp];
    }
    __syncthreads();
#pragma unroll
    for (int kk = 0; kk < 2; ++kk) {
      bf16x8 af[4], bfr[4];
#pragma unroll
      for (int fm = 0; fm < 4; ++fm)
        af[fm] = *(const bf16x8*)&At[wm + fm * 16 + (lane & 15)][(kk << 5) + ((lane >> 4) << 3)];
#pragma unroll
      for (int fn = 0; fn < 4; ++fn)
        bfr[fn] = *(const bf16x8*)&Bt[wn + fn * 16 + (lane & 15)][(kk << 5) + ((lane >> 4) << 3)];
#pragma unroll
      for (int fm = 0; fm < 4; ++fm)
#pragma unroll
        for (int fn = 0; fn < 4; ++fn)
          acc[fm][fn] = __builtin_amdgcn_mfma_f32_16x16x32_bf16(af[fm], bfr[fn], acc[fm][fn], 0, 0, 0);
    }
    __syncthreads();
  }
  // epilogue
  float bv[4];
#pragma unroll
  for (int fn = 0; fn < 4; ++fn) {
    if constexpr (MODE != 1) bv[fn] = bias[tn + wn + fn * 16 + (lane & 15)];
    else bv[fn] = 0.f;
  }
#pragma unroll
  for (int fm = 0; fm < 4; ++fm)
#pragma unroll
    for (int fn = 0; fn < 4; ++fn)
#pragma unroll
      for (int r = 0; r < 4; ++r) {
        int row = tm + wm + fm * 16 + ((lane >> 4) << 2) + r;
        int col = tn + wn + fn * 16 + (lane & 15);
        float v = acc[fm][fn][r] + bv[fn];
        if constexpr (MODE == 2) {
          Cf32[(size_t)(((row & 3) << 11) + (row >> 2)) * 1024 + col] = v;
        } else {
          Cbf[(size_t)row * N + col] = f2bf(v);
        }
      }
}

// ---------------- persistent scan kernel (single wave per block) ----------------
// 256 blocks x 64 threads, 1 block/CU. Block b owns INNER slice [8b, 8b+8).
// Per step: stage mixed_{t-1} (16 KB, plain loads -> PADDED LDS), MFMA dot
// D[j,bb] = sum_k Wcomb[j,k]*mixed[bb,k] (one 16x16x32 chain, K=2048),
// nonlinearity (lanes 0-31, tokens pre-fetched into registers last step),
// publish via RETURNING atomic swaps, vmcnt drain, 8-SPREAD counter add
// (cnt[(bid&7)<<5], 128B apart), poll = one wave-level 8-line atomic load
// (lanes 0-7) + shuffle-sum.
__global__ __launch_bounds__(64, 1) void scan_kernel(
    const unsigned short* __restrict__ wcombg,  // [4096][2048] bf16
    const float* __restrict__ bcombg,           // [4096]
    const float* __restrict__ sp0g,             // [4][4096]
    const unsigned short* __restrict__ projg,   // [8192][6144] bf16, m=b*2048+s
    unsigned short* __restrict__ mixedg,        // [2048][4][2048] bf16
    unsigned int* __restrict__ cnt)             // 8 counters, 128B apart, zeroed
{
  __shared__ __align__(16) unsigned short wcomb_lds[16][LSTR];  // 65.8 KB
  __shared__ __align__(16) unsigned short mixed_lds[5][LSTR];   // 20.6 KB, row4 = zeros
  __shared__ __align__(16) float spbuf[16][4];
  __shared__ __align__(16) float bcomb_lds[16];
  __shared__ __align__(16) unsigned short nlbuf[4][8];

  const int lane = threadIdx.x, bid = blockIdx.x;
  const int I0 = bid * 8;
  const int col = lane & 15;            // MFMA row/col index
  const int krow = (lane >> 4) << 3;    // MFMA k-subgroup offset

  // ---- prologue: stage Wcomb slice (u rows I0.., g rows 2048+I0..) ----
  for (int c = lane; c < 4096; c += 64) {
    int r = c >> 8, kp = (c & 255) << 3;
    int gj = (r < 8) ? (I0 + r) : (2048 + I0 + r - 8);
    *(uint4*)&wcomb_lds[r][kp] = *(const uint4*)&wcombg[((size_t)gj << 11) + kp];
  }
  // zero pad row (B-fragment source for unused MFMA cols 4..15)
  for (int c = lane; c < 256; c += 64) {
    uint4 z; z.x = 0; z.y = 0; z.z = 0; z.w = 0;
    ((uint4*)&mixed_lds[4][0])[c] = z;
  }
  if (lane < 16) bcomb_lds[lane] = bcombg[(lane < 8) ? (I0 + lane) : (2048 + I0 + lane - 8)];

  // ---- prologue: t=0 tokens + sp0 into registers (lanes 0..31) ----
  unsigned short rtu = 0, rtg = 0, rtv = 0;
  float su0 = 0.f, sg0 = 0.f;
  if (lane < 32) {
    const int i = lane & 7, bb = lane >> 3;
    size_t base = (size_t)(bb * 2048) * 6144 + I0 + i;
    rtu = projg[base];
    rtg = projg[base + 2048];
    rtv = projg[base + 4096];
    su0 = sp0g[bb * 4096 + I0 + i];
    sg0 = sp0g[bb * 4096 + 2048 + I0 + i];
  }
  WAIT_LGKM0();

  const unsigned short* arow = &wcomb_lds[col][0];
  const unsigned short* brow = &mixed_lds[(col < 4) ? col : 4][0];

#pragma unroll 1
  for (int t = 0; t < S_LEN; ++t) {
    float su = su0, sg = sg0;
    if (t > 0) {
      // ---- stage mixed_{t-1} (16 KB): plain loads -> padded LDS ----
      {
        const uint4* src = (const uint4*)(mixedg + ((size_t)(t - 1) << 13));
#pragma unroll
        for (int c = 0; c < 16; ++c) {
          int u = lane + (c << 6);               // uint4 index 0..1023
          uint4 v = src[u];
          *(uint4*)&mixed_lds[u >> 8][(u & 255) << 3] = v;   // 256 uint4/row
        }
      }
      WAIT_LGKM0();  // LDS writes complete (same wave)

      // ---- MFMA dot: D[j, bb] = sum_k W[j,k] * mx[bb,k] ----
      f32x4 acc = (f32x4)0.f;
#pragma unroll 4
      for (int k0 = 0; k0 < 2048; k0 += 32) {
        bf16x8 a = *(const bf16x8*)&arow[k0 + krow];
        bf16x8 b = *(const bf16x8*)&brow[k0 + krow];
        acc = __builtin_amdgcn_mfma_f32_16x16x32_bf16(a, b, acc, 0, 0, 0);
      }
      if (col < 4) {
#pragma unroll
        for (int r = 0; r < 4; ++r) spbuf[((lane >> 4) << 2) + r][col] = acc[r];
      }
      WAIT_LGKM0();  // spbuf visible within wave
      if (lane < 32) {
        const int i = lane & 7, bb = lane >> 3;
        su = spbuf[i][bb] + bcomb_lds[i];
        sg = spbuf[8 + i][bb] + bcomb_lds[8 + i];
      }
    }

    // ---- nonlinearity (lanes 0..31), tokens from registers ----
    if (lane < 32) {
      float tu = b2f(rtu), tg = b2f(rtg), tv = b2f(rtv);
      float cand = tanhf(tu + su);
      float gate = 1.0f / (1.0f + expf(-(tg + sg)));
      float mix = gate * cand + (1.0f - gate) * tanhf(tv);
      nlbuf[lane >> 3][lane & 7] = f2bf(mix);
    }
    WAIT_LGKM0();  // nlbuf visible within wave

    // ---- publish slice via RETURNING atomic swaps (performed at LLC) ----
    if (lane < 16) {
      const int bb = lane >> 2, g = lane & 3;
      unsigned lo = nlbuf[bb][2 * g], hi = nlbuf[bb][2 * g + 1];
      unsigned* dst = (unsigned*)(mixedg + ((size_t)t * 4 + bb) * 2048 + I0);
      unsigned old = __hip_atomic_exchange(dst + g, lo | (hi << 16),
                                           __ATOMIC_RELAXED, __HIP_MEMORY_SCOPE_AGENT);
      asm volatile("" :: "v"(old));  // keep returning form live (sc0)
    }

    if (t < S_LEN - 1) {
      WAIT_VM0();  // swaps performed at LLC
      if (lane == 0)
        __hip_atomic_fetch_add(&cnt[(bid & 7) << 5], 1u,
                               __ATOMIC_RELAXED, __HIP_MEMORY_SCOPE_AGENT);
      // ---- token prefetch for step t+1 (hidden under poll + stage + dot) ----
      if (lane < 32) {
        const int i = lane & 7, bb = lane >> 3;
        size_t base = (size_t)(bb * 2048 + t + 1) * 6144 + I0 + i;
        rtu = projg[base];
        rtg = projg[base + 2048];
        rtv = projg[base + 4096];
      }
      // ---- poll: sum of 8 spread counters, one wave-level load + shuffles ----
      const unsigned tgt = (unsigned)(t + 1) << 8;  // 256*(t+1)
      for (;;) {
        unsigned v = (lane < 8)
            ? __hip_atomic_load(&cnt[lane << 5], __ATOMIC_RELAXED, __HIP_MEMORY_SCOPE_AGENT)
            : 0u;
        v += __shfl_xor(v, 1);
        v += __shfl_xor(v, 2);
        v += __shfl_xor(v, 4);
        if (__shfl(v, 0) >= tgt) break;
        __builtin_amdgcn_s_sleep(1);
      }
    }
  }
}

extern "C" void kernel_launch(void* const* d_in, const int* in_sizes, int n_in,
                              void* d_out, int out_size, void* d_ws, size_t ws_size,
                              hipStream_t stream) {
  (void)in_sizes; (void)n_in; (void)out_size; (void)ws_size;
  const float* hidden = (const float*)d_in[0];
  const float* state0 = (const float*)d_in[1];
  const float* w_in   = (const float*)d_in[2];
  const float* b_in   = (const float*)d_in[3];
  const float* w_sp   = (const float*)d_in[4];
  const float* b_sp   = (const float*)d_in[5];
  const float* w_out  = (const float*)d_in[6];
  const float* b_out  = (const float*)d_in[7];
  const float* w_up   = (const float*)d_in[8];
  const float* b_up   = (const float*)d_in[9];
  float* out = (float*)d_out;
  char* ws = (char*)d_ws;

  size_t o = 0;
  auto take = [&](size_t b) { size_t p = o; o += (b + 255) & ~(size_t)255; return p; };
  unsigned* cntp         = (unsigned*)(ws + take(256 * 4));
  float* sp0p            = (float*)(ws + take((size_t)4 * 4096 * 4));
  float* bcombp          = (float*)(ws + take((size_t)4096 * 4));
  unsigned short* hbf    = (unsigned short*)(ws + take((size_t)8192 * 1024 * 2));
  unsigned short* winbf  = (unsigned short*)(ws + take((size_t)6144 * 1024 * 2));
  unsigned short* wspbf  = (unsigned short*)(ws + take((size_t)4096 * 512 * 2));
  unsigned short* wupTbf = (unsigned short*)(ws + take((size_t)2048 * 512 * 2));
  unsigned short* woutbf = (unsigned short*)(ws + take((size_t)1024 * 2048 * 2));
  unsigned short* wcombbf= (unsigned short*)(ws + take((size_t)4096 * 2048 * 2));
  unsigned short* projbf = (unsigned short*)(ws + take((size_t)8192 * 6144 * 2));
  unsigned short* mixbf  = (unsigned short*)(ws + take((size_t)8192 * 2048 * 2));

  hipMemsetAsync(cntp, 0, 256 * 4, stream);

  conv_f32_bf16<<<4096, 256, 0, stream>>>(hidden, hbf, 1048576);
  conv_f32_bf16<<<3072, 256, 0, stream>>>(w_in, winbf, 786432);
  conv_f32_bf16<<<1024, 256, 0, stream>>>(w_sp, wspbf, 262144);
  conv_f32_bf16<<<1024, 256, 0, stream>>>(w_out, woutbf, 262144);
  transpose_wup<<<4096, 256, 0, stream>>>(w_up, wupTbf);

  // projected = hidden @ in_proj_w^T + b_in   [8192, 6144] bf16
  gemm_bt<0><<<dim3(64, 48), 256, 0, stream>>>(hbf, winbf, projbf, nullptr, b_in, 8192, 6144, 1024);
  // Wcomb = Wsp @ Wup   [4096, 2048] bf16  (B = Wup^T as [2048,512])
  gemm_bt<1><<<dim3(32, 16), 256, 0, stream>>>(wspbf, wupTbf, wcombbf, nullptr, nullptr, 4096, 2048, 512);

  bcomb_kernel<<<1024, 256, 0, stream>>>(w_sp, b_sp, b_up, bcombp);
  sp0_kernel<<<1024, 256, 0, stream>>>(w_sp, b_sp, state0, sp0p);

  {
    const unsigned short* a0 = wcombbf;
    const float* a1 = bcombp;
    const float* a2 = sp0p;
    const unsigned short* a3 = projbf;
    unsigned short* a4 = mixbf;
    unsigned* a5 = cntp;
    void* args[] = {&a0, &a1, &a2, &a3, &a4, &a5};
    hipLaunchCooperativeKernel((const void*)scan_kernel, dim3(NBLK), dim3(64), args, 0, stream);
  }

  // out = mixed @ out_proj_w^T + b_out  -> fp32, remapped to [B,S,D]
  gemm_bt<2><<<dim3(64, 8), 256, 0, stream>>>(mixbf, woutbf, nullptr, out, b_out, 8192, 1024, 2048);
  final_state_kernel<<<128, 256, 0, stream>>>(w_up, b_up, mixbf, out + (size_t)8192 * 1024);
}

// Round 13
// 8812.366 us; speedup vs baseline: 2.5731x; 1.0382x over previous
//
#include <hip/hip_runtime.h>
#include <hip/hip_bf16.h>

// Problem: B=4, S=2048, D=1024, INNER=2048, STATE=512.
// out = out_proj(scan(in_proj(hidden)));  scan folded via Wcomb = Wsp @ Wup.
// Round 13 = round-12 (PASS, 9.15ms) + ONE change: the 64-deep dependent MFMA
// chain in the scan dot is split into 4 independent accumulator chains
// (summed at the end). Tests dep-latency (~17cyc) vs issue-rate (~5cyc) and
// forensically isolates one of r8's three suspects. Everything else identical.

#define S_LEN 2048
#define NBATCH 4
#define NBLK 256
#define LSTR 2056  // padded LDS row stride in bf16 (4112 B, 16B-aligned)

typedef __attribute__((ext_vector_type(4))) float f32x4;
typedef __attribute__((ext_vector_type(8))) short bf16x8;

__device__ __forceinline__ unsigned short f2bf(float f) {
  unsigned u = __builtin_bit_cast(unsigned, f);
  u += 0x7FFFu + ((u >> 16) & 1u);
  return (unsigned short)(u >> 16);
}
__device__ __forceinline__ float b2f(unsigned short s) { return __builtin_bit_cast(float, (unsigned)s << 16); }

__device__ __forceinline__ float wave_sum64(float v) {
#pragma unroll
  for (int m = 32; m >= 1; m >>= 1) v += __shfl_xor(v, m, 64);
  return v;
}

#define WAIT_VM0()   asm volatile("s_waitcnt vmcnt(0)" ::: "memory")
#define WAIT_LGKM0() asm volatile("s_waitcnt lgkmcnt(0)" ::: "memory")

// ---------------- fp32 -> bf16 convert (8 elems/thread) ----------------
__global__ void conv_f32_bf16(const float* __restrict__ in, unsigned short* __restrict__ out, int n8) {
  int g = blockIdx.x * 256 + threadIdx.x;
  if (g >= n8) return;
  const float4* p = (const float4*)in + 2 * (size_t)g;
  float4 a = p[0], b = p[1];
  uint4 o;
  o.x = (unsigned)f2bf(a.x) | ((unsigned)f2bf(a.y) << 16);
  o.y = (unsigned)f2bf(a.z) | ((unsigned)f2bf(a.w) << 16);
  o.z = (unsigned)f2bf(b.x) | ((unsigned)f2bf(b.y) << 16);
  o.w = (unsigned)f2bf(b.z) | ((unsigned)f2bf(b.w) << 16);
  ((uint4*)out)[g] = o;
}

// ---------------- Wup [512][2048] -> WupT bf16 [2048][512] ----------------
__global__ void transpose_wup(const float* __restrict__ in, unsigned short* __restrict__ out) {
  int g = blockIdx.x * 256 + threadIdx.x; // over 2048*512
  int i = g >> 9, k = g & 511;
  out[g] = f2bf(in[(size_t)k * 2048 + i]);
}

// ---------------- b_comb[j] = b_sp[j] + sum_k Wsp[j,k]*b_up[k] ----------------
__global__ void bcomb_kernel(const float* __restrict__ wsp, const float* __restrict__ bsp,
                             const float* __restrict__ bup, float* __restrict__ bcomb) {
  int wv = (blockIdx.x * 256 + threadIdx.x) >> 6;
  int lane = threadIdx.x & 63;
  if (wv >= 4096) return;
  float s = 0.f;
  for (int k = lane; k < 512; k += 64) s += wsp[(size_t)wv * 512 + k] * bup[k];
  s = wave_sum64(s);
  if (lane == 0) bcomb[wv] = s + bsp[wv];
}

// ---------------- sp0[b][j] = b_sp[j] + sum_k state0[b,k]*Wsp[j,k] ----------------
__global__ void sp0_kernel(const float* __restrict__ wsp, const float* __restrict__ bsp,
                           const float* __restrict__ state0, float* __restrict__ sp0) {
  int wv = (blockIdx.x * 256 + threadIdx.x) >> 6;
  int lane = threadIdx.x & 63;
  if (wv >= 4096) return;
  float acc[NBATCH] = {0.f, 0.f, 0.f, 0.f};
  for (int k = lane; k < 512; k += 64) {
    float w = wsp[(size_t)wv * 512 + k];
#pragma unroll
    for (int bb = 0; bb < NBATCH; ++bb) acc[bb] += state0[bb * 512 + k] * w;
  }
#pragma unroll
  for (int bb = 0; bb < NBATCH; ++bb) acc[bb] = wave_sum64(acc[bb]);
  if (lane == 0) {
    float b = bsp[wv];
#pragma unroll
    for (int bb = 0; bb < NBATCH; ++bb) sp0[bb * 4096 + wv] = acc[bb] + b;
  }
}

// ---------------- final_state[b][j] = b_up[j] + sum_i mixed[2047,b,i]*Wup[j,i] ----------------
__global__ void final_state_kernel(const float* __restrict__ wup, const float* __restrict__ bup,
                                   const unsigned short* __restrict__ mixedg, float* __restrict__ dst) {
  int wv = (blockIdx.x * 256 + threadIdx.x) >> 6;
  int lane = threadIdx.x & 63;
  if (wv >= 512) return;
  float acc[NBATCH] = {0.f, 0.f, 0.f, 0.f};
  for (int i = lane; i < 2048; i += 64) {
    float w = wup[(size_t)wv * 2048 + i];
#pragma unroll
    for (int bb = 0; bb < NBATCH; ++bb)
      acc[bb] += b2f(mixedg[((size_t)2047 * 4 + bb) * 2048 + i]) * w;
  }
#pragma unroll
  for (int bb = 0; bb < NBATCH; ++bb) acc[bb] = wave_sum64(acc[bb]);
  if (lane == 0) {
    float b = bup[wv];
#pragma unroll
    for (int bb = 0; bb < NBATCH; ++bb) dst[bb * 512 + wv] = acc[bb] + b;
  }
}

// ---------------- bf16 BT-GEMM: C[M,N] = A[M,K] @ B[N,K]^T (+bias) ----------------
// MODE 0: bf16 out + bias; MODE 1: bf16 out, no bias; MODE 2: fp32 out, bias,
// row remap m=s*4+b -> out[b][s][n] (S=2048, N=1024 hardcoded for out_proj).
template <int MODE>
__global__ __launch_bounds__(256) void gemm_bt(
    const unsigned short* __restrict__ A, const unsigned short* __restrict__ B,
    unsigned short* __restrict__ Cbf, float* __restrict__ Cf32,
    const float* __restrict__ bias, int M, int N, int K) {
  const int tm = blockIdx.x * 128, tn = blockIdx.y * 128;
  __shared__ __align__(16) unsigned short At[128][72];
  __shared__ __align__(16) unsigned short Bt[128][72];
  const int tid = threadIdx.x, lane = tid & 63, w = tid >> 6;
  const int wm = (w >> 1) * 64, wn = (w & 1) * 64;
  f32x4 acc[4][4];
#pragma unroll
  for (int a = 0; a < 4; ++a)
#pragma unroll
    for (int b = 0; b < 4; ++b) acc[a][b] = (f32x4)0.f;

  for (int k0 = 0; k0 < K; k0 += 64) {
#pragma unroll
    for (int it = 0; it < 4; ++it) {
      int c = tid + it * 256;
      int r = c >> 3, kp = (c & 7) * 8;
      *(uint4*)&At[r][kp] = *(const uint4*)&A[(size_t)(tm + r) * K + k0 + kp];
      *(uint4*)&Bt[r][kp] = *(const uint4*)&B[(size_t)(tn + r) * K + k0 + kp];
    }
    __syncthreads();
#pragma unroll
    for (int kk = 0; kk < 2; ++kk) {
      bf16x8 af[4], bfr[4];
#pragma unroll
      for (int fm = 0; fm < 4; ++fm)
        af[fm] = *(const bf16x8*)&At[wm + fm * 16 + (lane & 15)][(kk << 5) + ((lane >> 4) << 3)];
#pragma unroll
      for (int fn = 0; fn < 4; ++fn)
        bfr[fn] = *(const bf16x8*)&Bt[wn + fn * 16 + (lane & 15)][(kk << 5) + ((lane >> 4) << 3)];
#pragma unroll
      for (int fm = 0; fm < 4; ++fm)
#pragma unroll
        for (int fn = 0; fn < 4; ++fn)
          acc[fm][fn] = __builtin_amdgcn_mfma_f32_16x16x32_bf16(af[fm], bfr[fn], acc[fm][fn], 0, 0, 0);
    }
    __syncthreads();
  }
  // epilogue
  float bv[4];
#pragma unroll
  for (int fn = 0; fn < 4; ++fn) {
    if constexpr (MODE != 1) bv[fn] = bias[tn + wn + fn * 16 + (lane & 15)];
    else bv[fn] = 0.f;
  }
#pragma unroll
  for (int fm = 0; fm < 4; ++fm)
#pragma unroll
    for (int fn = 0; fn < 4; ++fn)
#pragma unroll
      for (int r = 0; r < 4; ++r) {
        int row = tm + wm + fm * 16 + ((lane >> 4) << 2) + r;
        int col = tn + wn + fn * 16 + (lane & 15);
        float v = acc[fm][fn][r] + bv[fn];
        if constexpr (MODE == 2) {
          Cf32[(size_t)(((row & 3) << 11) + (row >> 2)) * 1024 + col] = v;
        } else {
          Cbf[(size_t)row * N + col] = f2bf(v);
        }
      }
}

// ---------------- persistent scan kernel (single wave per block) ----------------
// 256 blocks x 64 threads, 1 block/CU. Block b owns INNER slice [8b, 8b+8).
// Per step: stage mixed_{t-1} (16 KB, plain loads -> PADDED LDS), MFMA dot
// with 4 INDEPENDENT accumulator chains (issue-rate-bound, not dep-latency),
// nonlinearity (lanes 0-31, tokens pre-fetched into registers last step),
// publish via RETURNING atomic swaps, vmcnt drain, 8-SPREAD counter add,
// poll = one wave-level 8-line atomic load + shuffle-sum.
__global__ __launch_bounds__(64, 1) void scan_kernel(
    const unsigned short* __restrict__ wcombg,  // [4096][2048] bf16
    const float* __restrict__ bcombg,           // [4096]
    const float* __restrict__ sp0g,             // [4][4096]
    const unsigned short* __restrict__ projg,   // [8192][6144] bf16, m=b*2048+s
    unsigned short* __restrict__ mixedg,        // [2048][4][2048] bf16
    unsigned int* __restrict__ cnt)             // 8 counters, 128B apart, zeroed
{
  __shared__ __align__(16) unsigned short wcomb_lds[16][LSTR];  // 65.8 KB
  __shared__ __align__(16) unsigned short mixed_lds[5][LSTR];   // 20.6 KB, row4 = zeros
  __shared__ __align__(16) float spbuf[16][4];
  __shared__ __align__(16) float bcomb_lds[16];
  __shared__ __align__(16) unsigned short nlbuf[4][8];

  const int lane = threadIdx.x, bid = blockIdx.x;
  const int I0 = bid * 8;
  const int col = lane & 15;            // MFMA row/col index
  const int krow = (lane >> 4) << 3;    // MFMA k-subgroup offset

  // ---- prologue: stage Wcomb slice (u rows I0.., g rows 2048+I0..) ----
  for (int c = lane; c < 4096; c += 64) {
    int r = c >> 8, kp = (c & 255) << 3;
    int gj = (r < 8) ? (I0 + r) : (2048 + I0 + r - 8);
    *(uint4*)&wcomb_lds[r][kp] = *(const uint4*)&wcombg[((size_t)gj << 11) + kp];
  }
  // zero pad row (B-fragment source for unused MFMA cols 4..15)
  for (int c = lane; c < 256; c += 64) {
    uint4 z; z.x = 0; z.y = 0; z.z = 0; z.w = 0;
    ((uint4*)&mixed_lds[4][0])[c] = z;
  }
  if (lane < 16) bcomb_lds[lane] = bcombg[(lane < 8) ? (I0 + lane) : (2048 + I0 + lane - 8)];

  // ---- prologue: t=0 tokens + sp0 into registers (lanes 0..31) ----
  unsigned short rtu = 0, rtg = 0, rtv = 0;
  float su0 = 0.f, sg0 = 0.f;
  if (lane < 32) {
    const int i = lane & 7, bb = lane >> 3;
    size_t base = (size_t)(bb * 2048) * 6144 + I0 + i;
    rtu = projg[base];
    rtg = projg[base + 2048];
    rtv = projg[base + 4096];
    su0 = sp0g[bb * 4096 + I0 + i];
    sg0 = sp0g[bb * 4096 + 2048 + I0 + i];
  }
  WAIT_LGKM0();

  const unsigned short* arow = &wcomb_lds[col][0];
  const unsigned short* brow = &mixed_lds[(col < 4) ? col : 4][0];

#pragma unroll 1
  for (int t = 0; t < S_LEN; ++t) {
    float su = su0, sg = sg0;
    if (t > 0) {
      // ---- stage mixed_{t-1} (16 KB): plain loads -> padded LDS ----
      {
        const uint4* src = (const uint4*)(mixedg + ((size_t)(t - 1) << 13));
#pragma unroll
        for (int c = 0; c < 16; ++c) {
          int u = lane + (c << 6);               // uint4 index 0..1023
          uint4 v = src[u];
          *(uint4*)&mixed_lds[u >> 8][(u & 255) << 3] = v;   // 256 uint4/row
        }
      }
      WAIT_LGKM0();  // LDS writes complete (same wave)

      // ---- MFMA dot: 4 independent chains (issue-rate, not dep-latency) ----
      f32x4 ac0 = (f32x4)0.f, ac1 = (f32x4)0.f, ac2 = (f32x4)0.f, ac3 = (f32x4)0.f;
#pragma unroll 4
      for (int k0 = 0; k0 < 2048; k0 += 128) {
        bf16x8 a0 = *(const bf16x8*)&arow[k0 + krow];
        bf16x8 b0 = *(const bf16x8*)&brow[k0 + krow];
        ac0 = __builtin_amdgcn_mfma_f32_16x16x32_bf16(a0, b0, ac0, 0, 0, 0);
        bf16x8 a1 = *(const bf16x8*)&arow[k0 + 32 + krow];
        bf16x8 b1 = *(const bf16x8*)&brow[k0 + 32 + krow];
        ac1 = __builtin_amdgcn_mfma_f32_16x16x32_bf16(a1, b1, ac1, 0, 0, 0);
        bf16x8 a2 = *(const bf16x8*)&arow[k0 + 64 + krow];
        bf16x8 b2 = *(const bf16x8*)&brow[k0 + 64 + krow];
        ac2 = __builtin_amdgcn_mfma_f32_16x16x32_bf16(a2, b2, ac2, 0, 0, 0);
        bf16x8 a3 = *(const bf16x8*)&arow[k0 + 96 + krow];
        bf16x8 b3 = *(const bf16x8*)&brow[k0 + 96 + krow];
        ac3 = __builtin_amdgcn_mfma_f32_16x16x32_bf16(a3, b3, ac3, 0, 0, 0);
      }
      f32x4 accT = (ac0 + ac1) + (ac2 + ac3);

      if (col < 4) {
#pragma unroll
        for (int r = 0; r < 4; ++r) spbuf[((lane >> 4) << 2) + r][col] = accT[r];
      }
      WAIT_LGKM0();  // spbuf visible within wave
      if (lane < 32) {
        const int i = lane & 7, bb = lane >> 3;
        su = spbuf[i][bb] + bcomb_lds[i];
        sg = spbuf[8 + i][bb] + bcomb_lds[8 + i];
      }
    }

    // ---- nonlinearity (lanes 0..31), tokens from registers ----
    if (lane < 32) {
      float tu = b2f(rtu), tg = b2f(rtg), tv = b2f(rtv);
      float cand = tanhf(tu + su);
      float gate = 1.0f / (1.0f + expf(-(tg + sg)));
      float mix = gate * cand + (1.0f - gate) * tanhf(tv);
      nlbuf[lane >> 3][lane & 7] = f2bf(mix);
    }
    WAIT_LGKM0();  // nlbuf visible within wave

    // ---- publish slice via RETURNING atomic swaps (performed at LLC) ----
    if (lane < 16) {
      const int bb = lane >> 2, g = lane & 3;
      unsigned lo = nlbuf[bb][2 * g], hi = nlbuf[bb][2 * g + 1];
      unsigned* dst = (unsigned*)(mixedg + ((size_t)t * 4 + bb) * 2048 + I0);
      unsigned old = __hip_atomic_exchange(dst + g, lo | (hi << 16),
                                           __ATOMIC_RELAXED, __HIP_MEMORY_SCOPE_AGENT);
      asm volatile("" :: "v"(old));  // keep returning form live (sc0)
    }

    if (t < S_LEN - 1) {
      WAIT_VM0();  // swaps performed at LLC
      if (lane == 0)
        __hip_atomic_fetch_add(&cnt[(bid & 7) << 5], 1u,
                               __ATOMIC_RELAXED, __HIP_MEMORY_SCOPE_AGENT);
      // ---- token prefetch for step t+1 (hidden under poll + stage + dot) ----
      if (lane < 32) {
        const int i = lane & 7, bb = lane >> 3;
        size_t base = (size_t)(bb * 2048 + t + 1) * 6144 + I0 + i;
        rtu = projg[base];
        rtg = projg[base + 2048];
        rtv = projg[base + 4096];
      }
      // ---- poll: sum of 8 spread counters, one wave-level load + shuffles ----
      const unsigned tgt = (unsigned)(t + 1) << 8;  // 256*(t+1)
      for (;;) {
        unsigned v = (lane < 8)
            ? __hip_atomic_load(&cnt[lane << 5], __ATOMIC_RELAXED, __HIP_MEMORY_SCOPE_AGENT)
            : 0u;
        v += __shfl_xor(v, 1);
        v += __shfl_xor(v, 2);
        v += __shfl_xor(v, 4);
        if (__shfl(v, 0) >= tgt) break;
        __builtin_amdgcn_s_sleep(1);
      }
    }
  }
}

extern "C" void kernel_launch(void* const* d_in, const int* in_sizes, int n_in,
                              void* d_out, int out_size, void* d_ws, size_t ws_size,
                              hipStream_t stream) {
  (void)in_sizes; (void)n_in; (void)out_size; (void)ws_size;
  const float* hidden = (const float*)d_in[0];
  const float* state0 = (const float*)d_in[1];
  const float* w_in   = (const float*)d_in[2];
  const float* b_in   = (const float*)d_in[3];
  const float* w_sp   = (const float*)d_in[4];
  const float* b_sp   = (const float*)d_in[5];
  const float* w_out  = (const float*)d_in[6];
  const float* b_out  = (const float*)d_in[7];
  const float* w_up   = (const float*)d_in[8];
  const float* b_up   = (const float*)d_in[9];
  float* out = (float*)d_out;
  char* ws = (char*)d_ws;

  size_t o = 0;
  auto take = [&](size_t b) { size_t p = o; o += (b + 255) & ~(size_t)255; return p; };
  unsigned* cntp         = (unsigned*)(ws + take(256 * 4));
  float* sp0p            = (float*)(ws + take((size_t)4 * 4096 * 4));
  float* bcombp          = (float*)(ws + take((size_t)4096 * 4));
  unsigned short* hbf    = (unsigned short*)(ws + take((size_t)8192 * 1024 * 2));
  unsigned short* winbf  = (unsigned short*)(ws + take((size_t)6144 * 1024 * 2));
  unsigned short* wspbf  = (unsigned short*)(ws + take((size_t)4096 * 512 * 2));
  unsigned short* wupTbf = (unsigned short*)(ws + take((size_t)2048 * 512 * 2));
  unsigned short* woutbf = (unsigned short*)(ws + take((size_t)1024 * 2048 * 2));
  unsigned short* wcombbf= (unsigned short*)(ws + take((size_t)4096 * 2048 * 2));
  unsigned short* projbf = (unsigned short*)(ws + take((size_t)8192 * 6144 * 2));
  unsigned short* mixbf  = (unsigned short*)(ws + take((size_t)8192 * 2048 * 2));

  hipMemsetAsync(cntp, 0, 256 * 4, stream);

  conv_f32_bf16<<<4096, 256, 0, stream>>>(hidden, hbf, 1048576);
  conv_f32_bf16<<<3072, 256, 0, stream>>>(w_in, winbf, 786432);
  conv_f32_bf16<<<1024, 256, 0, stream>>>(w_sp, wspbf, 262144);
  conv_f32_bf16<<<1024, 256, 0, stream>>>(w_out, woutbf, 262144);
  transpose_wup<<<4096, 256, 0, stream>>>(w_up, wupTbf);

  // projected = hidden @ in_proj_w^T + b_in   [8192, 6144] bf16
  gemm_bt<0><<<dim3(64, 48), 256, 0, stream>>>(hbf, winbf, projbf, nullptr, b_in, 8192, 6144, 1024);
  // Wcomb = Wsp @ Wup   [4096, 2048] bf16  (B = Wup^T as [2048,512])
  gemm_bt<1><<<dim3(32, 16), 256, 0, stream>>>(wspbf, wupTbf, wcombbf, nullptr, nullptr, 4096, 2048, 512);

  bcomb_kernel<<<1024, 256, 0, stream>>>(w_sp, b_sp, b_up, bcombp);
  sp0_kernel<<<1024, 256, 0, stream>>>(w_sp, b_sp, state0, sp0p);

  {
    const unsigned short* a0 = wcombbf;
    const float* a1 = bcombp;
    const float* a2 = sp0p;
    const unsigned short* a3 = projbf;
    unsigned short* a4 = mixbf;
    unsigned* a5 = cntp;
    void* args[] = {&a0, &a1, &a2, &a3, &a4, &a5};
    hipLaunchCooperativeKernel((const void*)scan_kernel, dim3(NBLK), dim3(64), args, 0, stream);
  }

  // out = mixed @ out_proj_w^T + b_out  -> fp32, remapped to [B,S,D]
  gemm_bt<2><<<dim3(64, 8), 256, 0, stream>>>(mixbf, woutbf, nullptr, out, b_out, 8192, 1024, 2048);
  final_state_kernel<<<128, 256, 0, stream>>>(w_up, b_up, mixbf, out + (size_t)8192 * 1024);
}

// Round 15
// 7005.218 us; speedup vs baseline: 3.2369x; 1.2580x over previous
//
#include <hip/hip_runtime.h>
#include <hip/hip_bf16.h>

// Problem: B=4, S=2048, D=1024, INNER=2048, STATE=512.
// out = out_proj(scan(in_proj(hidden)));  scan folded via Wcomb = Wsp @ Wup.
// Round 15 = round-13 (PASS, 8.81ms) + ONE structural change: stage+dot
// parallelized across 4 waves (256-thread blocks), split by K so each wave
// stages and consumes its own quarter (no stage->dot barrier). One
// __syncthreads per step for the partial-sum reduce. Protocol (publish swaps,
// 8-spread counter, poll) byte-identical to r13.
// CONVICTED (do not reintroduce): A-fragments in VGPRs (afr[64]) — r7/r8/r14
// all failed with identical absmax; scan silently contributes nothing.

#define S_LEN 2048
#define NBATCH 4
#define NBLK 256
#define LSTR 2056  // padded LDS row stride in bf16 (4112 B, 16B-aligned)

typedef __attribute__((ext_vector_type(4))) float f32x4;
typedef __attribute__((ext_vector_type(8))) short bf16x8;

__device__ __forceinline__ unsigned short f2bf(float f) {
  unsigned u = __builtin_bit_cast(unsigned, f);
  u += 0x7FFFu + ((u >> 16) & 1u);
  return (unsigned short)(u >> 16);
}
__device__ __forceinline__ float b2f(unsigned short s) { return __builtin_bit_cast(float, (unsigned)s << 16); }

__device__ __forceinline__ float wave_sum64(float v) {
#pragma unroll
  for (int m = 32; m >= 1; m >>= 1) v += __shfl_xor(v, m, 64);
  return v;
}

#define WAIT_VM0()   asm volatile("s_waitcnt vmcnt(0)" ::: "memory")
#define WAIT_LGKM0() asm volatile("s_waitcnt lgkmcnt(0)" ::: "memory")

// ---------------- fp32 -> bf16 convert (8 elems/thread) ----------------
__global__ void conv_f32_bf16(const float* __restrict__ in, unsigned short* __restrict__ out, int n8) {
  int g = blockIdx.x * 256 + threadIdx.x;
  if (g >= n8) return;
  const float4* p = (const float4*)in + 2 * (size_t)g;
  float4 a = p[0], b = p[1];
  uint4 o;
  o.x = (unsigned)f2bf(a.x) | ((unsigned)f2bf(a.y) << 16);
  o.y = (unsigned)f2bf(a.z) | ((unsigned)f2bf(a.w) << 16);
  o.z = (unsigned)f2bf(b.x) | ((unsigned)f2bf(b.y) << 16);
  o.w = (unsigned)f2bf(b.z) | ((unsigned)f2bf(b.w) << 16);
  ((uint4*)out)[g] = o;
}

// ---------------- Wup [512][2048] -> WupT bf16 [2048][512] ----------------
__global__ void transpose_wup(const float* __restrict__ in, unsigned short* __restrict__ out) {
  int g = blockIdx.x * 256 + threadIdx.x; // over 2048*512
  int i = g >> 9, k = g & 511;
  out[g] = f2bf(in[(size_t)k * 2048 + i]);
}

// ---------------- b_comb[j] = b_sp[j] + sum_k Wsp[j,k]*b_up[k] ----------------
__global__ void bcomb_kernel(const float* __restrict__ wsp, const float* __restrict__ bsp,
                             const float* __restrict__ bup, float* __restrict__ bcomb) {
  int wv = (blockIdx.x * 256 + threadIdx.x) >> 6;
  int lane = threadIdx.x & 63;
  if (wv >= 4096) return;
  float s = 0.f;
  for (int k = lane; k < 512; k += 64) s += wsp[(size_t)wv * 512 + k] * bup[k];
  s = wave_sum64(s);
  if (lane == 0) bcomb[wv] = s + bsp[wv];
}

// ---------------- sp0[b][j] = b_sp[j] + sum_k state0[b,k]*Wsp[j,k] ----------------
__global__ void sp0_kernel(const float* __restrict__ wsp, const float* __restrict__ bsp,
                           const float* __restrict__ state0, float* __restrict__ sp0) {
  int wv = (blockIdx.x * 256 + threadIdx.x) >> 6;
  int lane = threadIdx.x & 63;
  if (wv >= 4096) return;
  float acc[NBATCH] = {0.f, 0.f, 0.f, 0.f};
  for (int k = lane; k < 512; k += 64) {
    float w = wsp[(size_t)wv * 512 + k];
#pragma unroll
    for (int bb = 0; bb < NBATCH; ++bb) acc[bb] += state0[bb * 512 + k] * w;
  }
#pragma unroll
  for (int bb = 0; bb < NBATCH; ++bb) acc[bb] = wave_sum64(acc[bb]);
  if (lane == 0) {
    float b = bsp[wv];
#pragma unroll
    for (int bb = 0; bb < NBATCH; ++bb) sp0[bb * 4096 + wv] = acc[bb] + b;
  }
}

// ---------------- final_state[b][j] = b_up[j] + sum_i mixed[2047,b,i]*Wup[j,i] ----------------
__global__ void final_state_kernel(const float* __restrict__ wup, const float* __restrict__ bup,
                                   const unsigned short* __restrict__ mixedg, float* __restrict__ dst) {
  int wv = (blockIdx.x * 256 + threadIdx.x) >> 6;
  int lane = threadIdx.x & 63;
  if (wv >= 512) return;
  float acc[NBATCH] = {0.f, 0.f, 0.f, 0.f};
  for (int i = lane; i < 2048; i += 64) {
    float w = wup[(size_t)wv * 2048 + i];
#pragma unroll
    for (int bb = 0; bb < NBATCH; ++bb)
      acc[bb] += b2f(mixedg[((size_t)2047 * 4 + bb) * 2048 + i]) * w;
  }
#pragma unroll
  for (int bb = 0; bb < NBATCH; ++bb) acc[bb] = wave_sum64(acc[bb]);
  if (lane == 0) {
    float b = bup[wv];
#pragma unroll
    for (int bb = 0; bb < NBATCH; ++bb) dst[bb * 512 + wv] = acc[bb] + b;
  }
}

// ---------------- bf16 BT-GEMM: C[M,N] = A[M,K] @ B[N,K]^T (+bias) ----------------
// MODE 0: bf16 out + bias; MODE 1: bf16 out, no bias; MODE 2: fp32 out, bias,
// row remap m=s*4+b -> out[b][s][n] (S=2048, N=1024 hardcoded for out_proj).
template <int MODE>
__global__ __launch_bounds__(256) void gemm_bt(
    const unsigned short* __restrict__ A, const unsigned short* __restrict__ B,
    unsigned short* __restrict__ Cbf, float* __restrict__ Cf32,
    const float* __restrict__ bias, int M, int N, int K) {
  const int tm = blockIdx.x * 128, tn = blockIdx.y * 128;
  __shared__ __align__(16) unsigned short At[128][72];
  __shared__ __align__(16) unsigned short Bt[128][72];
  const int tid = threadIdx.x, lane = tid & 63, w = tid >> 6;
  const int wm = (w >> 1) * 64, wn = (w & 1) * 64;
  f32x4 acc[4][4];
#pragma unroll
  for (int a = 0; a < 4; ++a)
#pragma unroll
    for (int b = 0; b < 4; ++b) acc[a][b] = (f32x4)0.f;

  for (int k0 = 0; k0 < K; k0 += 64) {
#pragma unroll
    for (int it = 0; it < 4; ++it) {
      int c = tid + it * 256;
      int r = c >> 3, kp = (c & 7) * 8;
      *(uint4*)&At[r][kp] = *(const uint4*)&A[(size_t)(tm + r) * K + k0 + kp];
      *(uint4*)&Bt[r][kp] = *(const uint4*)&B[(size_t)(tn + r) * K + k0 + kp];
    }
    __syncthreads();
#pragma unroll
    for (int kk = 0; kk < 2; ++kk) {
      bf16x8 af[4], bfr[4];
#pragma unroll
      for (int fm = 0; fm < 4; ++fm)
        af[fm] = *(const bf16x8*)&At[wm + fm * 16 + (lane & 15)][(kk << 5) + ((lane >> 4) << 3)];
#pragma unroll
      for (int fn = 0; fn < 4; ++fn)
        bfr[fn] = *(const bf16x8*)&Bt[wn + fn * 16 + (lane & 15)][(kk << 5) + ((lane >> 4) << 3)];
#pragma unroll
      for (int fm = 0; fm < 4; ++fm)
#pragma unroll
        for (int fn = 0; fn < 4; ++fn)
          acc[fm][fn] = __builtin_amdgcn_mfma_f32_16x16x32_bf16(af[fm], bfr[fn], acc[fm][fn], 0, 0, 0);
    }
    __syncthreads();
  }
  // epilogue
  float bv[4];
#pragma unroll
  for (int fn = 0; fn < 4; ++fn) {
    if constexpr (MODE != 1) bv[fn] = bias[tn + wn + fn * 16 + (lane & 15)];
    else bv[fn] = 0.f;
  }
#pragma unroll
  for (int fm = 0; fm < 4; ++fm)
#pragma unroll
    for (int fn = 0; fn < 4; ++fn)
#pragma unroll
      for (int r = 0; r < 4; ++r) {
        int row = tm + wm + fm * 16 + ((lane >> 4) << 2) + r;
        int col = tn + wn + fn * 16 + (lane & 15);
        float v = acc[fm][fn][r] + bv[fn];
        if constexpr (MODE == 2) {
          Cf32[(size_t)(((row & 3) << 11) + (row >> 2)) * 1024 + col] = v;
        } else {
          Cbf[(size_t)row * N + col] = f2bf(v);
        }
      }
}

// ---------------- persistent scan kernel (4 waves per block) ----------------
// 256 blocks x 256 threads, 1 block/CU. Block b owns INNER slice [8b, 8b+8).
// K-split across waves: wave w stages B-columns [512w,512w+512) of mixed_{t-1}
// (rows 0-3) and computes MFMAs m in [16w,16w+16) over that same quarter (no
// stage->dot barrier needed). Partial sums -> spbufp[w]; ONE __syncthreads;
// wave0 reduces 4 partials, nonlinearity, publish via RETURNING atomic swaps,
// vmcnt drain, 8-SPREAD counter add; ALL waves poll independently.
__global__ __launch_bounds__(256, 1) void scan_kernel(
    const unsigned short* __restrict__ wcombg,  // [4096][2048] bf16
    const float* __restrict__ bcombg,           // [4096]
    const float* __restrict__ sp0g,             // [4][4096]
    const unsigned short* __restrict__ projg,   // [8192][6144] bf16, m=b*2048+s
    unsigned short* __restrict__ mixedg,        // [2048][4][2048] bf16
    unsigned int* __restrict__ cnt)             // 8 counters, 128B apart, zeroed
{
  __shared__ __align__(16) unsigned short wcomb_lds[16][LSTR];  // 65.8 KB
  __shared__ __align__(16) unsigned short mixed_lds[5][LSTR];   // 20.6 KB, row4 = zeros
  __shared__ __align__(16) float spbufp[4][16][4];              // per-wave partials
  __shared__ __align__(16) float bcomb_lds[16];
  __shared__ __align__(16) unsigned short nlbuf[4][8];

  const int tid = threadIdx.x, bid = blockIdx.x;
  const int lane = tid & 63, w = tid >> 6;
  const int I0 = bid * 8;
  const int col = lane & 15;            // MFMA row/col index
  const int krow = (lane >> 4) << 3;    // MFMA k-subgroup offset
  const int m0 = w << 4;                // wave's MFMA k-chunk start (m in [m0,m0+16))

  // ---- prologue: stage Wcomb slice (u rows I0.., g rows 2048+I0..), 256 thr ----
  for (int c = tid; c < 4096; c += 256) {
    int r = c >> 8, kp = (c & 255) << 3;
    int gj = (r < 8) ? (I0 + r) : (2048 + I0 + r - 8);
    *(uint4*)&wcomb_lds[r][kp] = *(const uint4*)&wcombg[((size_t)gj << 11) + kp];
  }
  // zero pad row (B-fragment source for unused MFMA cols 4..15)
  {
    uint4 z; z.x = 0; z.y = 0; z.z = 0; z.w = 0;
    ((uint4*)&mixed_lds[4][0])[tid & 255] = z;
  }
  if (tid < 16) bcomb_lds[tid] = bcombg[(tid < 8) ? (I0 + tid) : (2048 + I0 + tid - 8)];

  // ---- prologue: t=0 tokens + sp0 into registers (wave0 lanes 0..31) ----
  unsigned short rtu = 0, rtg = 0, rtv = 0;
  float su0 = 0.f, sg0 = 0.f;
  if (tid < 32) {
    const int i = tid & 7, bb = tid >> 3;
    size_t base = (size_t)(bb * 2048) * 6144 + I0 + i;
    rtu = projg[base];
    rtg = projg[base + 2048];
    rtv = projg[base + 4096];
    su0 = sp0g[bb * 4096 + I0 + i];
    sg0 = sp0g[bb * 4096 + 2048 + I0 + i];
  }
  __syncthreads();  // wcomb + pad row + bcomb ready for all waves

  const unsigned short* arow = &wcomb_lds[col][0];
  const unsigned short* brow = &mixed_lds[(col < 4) ? col : 4][0];

#pragma unroll 1
  for (int t = 0; t < S_LEN; ++t) {
    if (t > 0) {
      // ---- stage own K-quarter of mixed_{t-1}: u = tid + c*256 -> row u>>8,
      //      k8 = u&255 = tid -> wave w covers k in [512w, 512w+512), rows 0..3
      {
        const uint4* src = (const uint4*)(mixedg + ((size_t)(t - 1) << 13));
#pragma unroll
        for (int c = 0; c < 4; ++c) {
          int u = tid + (c << 8);
          uint4 v = src[u];
          *(uint4*)&mixed_lds[u >> 8][(u & 255) << 3] = v;
        }
      }
      WAIT_LGKM0();  // own quarter's LDS writes complete (same wave)

      // ---- dot over own quarter: m in [m0, m0+16), 4 independent chains ----
      f32x4 ac0 = (f32x4)0.f, ac1 = (f32x4)0.f, ac2 = (f32x4)0.f, ac3 = (f32x4)0.f;
#pragma unroll
      for (int mm = 0; mm < 16; mm += 4) {
        const int m = m0 + mm;
        bf16x8 a0 = *(const bf16x8*)&arow[(m << 5) + krow];
        bf16x8 b0 = *(const bf16x8*)&brow[(m << 5) + krow];
        ac0 = __builtin_amdgcn_mfma_f32_16x16x32_bf16(a0, b0, ac0, 0, 0, 0);
        bf16x8 a1 = *(const bf16x8*)&arow[((m + 1) << 5) + krow];
        bf16x8 b1 = *(const bf16x8*)&brow[((m + 1) << 5) + krow];
        ac1 = __builtin_amdgcn_mfma_f32_16x16x32_bf16(a1, b1, ac1, 0, 0, 0);
        bf16x8 a2 = *(const bf16x8*)&arow[((m + 2) << 5) + krow];
        bf16x8 b2 = *(const bf16x8*)&brow[((m + 2) << 5) + krow];
        ac2 = __builtin_amdgcn_mfma_f32_16x16x32_bf16(a2, b2, ac2, 0, 0, 0);
        bf16x8 a3 = *(const bf16x8*)&arow[((m + 3) << 5) + krow];
        bf16x8 b3 = *(const bf16x8*)&brow[((m + 3) << 5) + krow];
        ac3 = __builtin_amdgcn_mfma_f32_16x16x32_bf16(a3, b3, ac3, 0, 0, 0);
      }
      f32x4 accT = (ac0 + ac1) + (ac2 + ac3);
      if (col < 4) {
#pragma unroll
        for (int r = 0; r < 4; ++r) spbufp[w][((lane >> 4) << 2) + r][col] = accT[r];
      }
    }
    __syncthreads();  // spbufp[0..3] ready (compiler drains lgkmcnt before barrier)

    // ---- nonlinearity (wave0 lanes 0..31): reduce 4 partials + bias ----
    if (tid < 32) {
      float su = su0, sg = sg0;
      const int i = tid & 7, bb = tid >> 3;
      if (t > 0) {
        su = (spbufp[0][i][bb] + spbufp[1][i][bb]) +
             (spbufp[2][i][bb] + spbufp[3][i][bb]) + bcomb_lds[i];
        sg = (spbufp[0][8 + i][bb] + spbufp[1][8 + i][bb]) +
             (spbufp[2][8 + i][bb] + spbufp[3][8 + i][bb]) + bcomb_lds[8 + i];
      }
      float tu = b2f(rtu), tg = b2f(rtg), tv = b2f(rtv);
      float cand = tanhf(tu + su);
      float gate = 1.0f / (1.0f + expf(-(tg + sg)));
      float mix = gate * cand + (1.0f - gate) * tanhf(tv);
      nlbuf[bb][i] = f2bf(mix);
    }

    if (w == 0) {
      WAIT_LGKM0();  // nlbuf + spbufp reads complete within wave 0
      // ---- publish slice via RETURNING atomic swaps (performed at LLC) ----
      if (tid < 16) {
        const int bb = tid >> 2, g = tid & 3;
        unsigned lo = nlbuf[bb][2 * g], hi = nlbuf[bb][2 * g + 1];
        unsigned* dst = (unsigned*)(mixedg + ((size_t)t * 4 + bb) * 2048 + I0);
        unsigned old = __hip_atomic_exchange(dst + g, lo | (hi << 16),
                                             __ATOMIC_RELAXED, __HIP_MEMORY_SCOPE_AGENT);
        asm volatile("" :: "v"(old));  // keep returning form live (sc0)
      }
      if (t < S_LEN - 1) {
        WAIT_VM0();  // swaps performed at LLC
        if (tid == 0)
          __hip_atomic_fetch_add(&cnt[(bid & 7) << 5], 1u,
                                 __ATOMIC_RELAXED, __HIP_MEMORY_SCOPE_AGENT);
        // ---- token prefetch for step t+1 (wave0, hidden under poll) ----
        if (tid < 32) {
          const int i = tid & 7, bb = tid >> 3;
          size_t base = (size_t)(bb * 2048 + t + 1) * 6144 + I0 + i;
          rtu = projg[base];
          rtg = projg[base + 2048];
          rtv = projg[base + 4096];
        }
      }
    }

    if (t < S_LEN - 1) {
      // ---- ALL waves poll the 8 spread counters independently; release is
      //      transitive through our own block's add (after wave0's reads) ----
      const unsigned tgt = (unsigned)(t + 1) << 8;  // 256*(t+1)
      for (;;) {
        unsigned v = (lane < 8)
            ? __hip_atomic_load(&cnt[lane << 5], __ATOMIC_RELAXED, __HIP_MEMORY_SCOPE_AGENT)
            : 0u;
        v += __shfl_xor(v, 1);
        v += __shfl_xor(v, 2);
        v += __shfl_xor(v, 4);
        if (__shfl(v, 0) >= tgt) break;
        __builtin_amdgcn_s_sleep(1);
      }
    }
  }
}

extern "C" void kernel_launch(void* const* d_in, const int* in_sizes, int n_in,
                              void* d_out, int out_size, void* d_ws, size_t ws_size,
                              hipStream_t stream) {
  (void)in_sizes; (void)n_in; (void)out_size; (void)ws_size;
  const float* hidden = (const float*)d_in[0];
  const float* state0 = (const float*)d_in[1];
  const float* w_in   = (const float*)d_in[2];
  const float* b_in   = (const float*)d_in[3];
  const float* w_sp   = (const float*)d_in[4];
  const float* b_sp   = (const float*)d_in[5];
  const float* w_out  = (const float*)d_in[6];
  const float* b_out  = (const float*)d_in[7];
  const float* w_up   = (const float*)d_in[8];
  const float* b_up   = (const float*)d_in[9];
  float* out = (float*)d_out;
  char* ws = (char*)d_ws;

  size_t o = 0;
  auto take = [&](size_t b) { size_t p = o; o += (b + 255) & ~(size_t)255; return p; };
  unsigned* cntp         = (unsigned*)(ws + take(256 * 4));
  float* sp0p            = (float*)(ws + take((size_t)4 * 4096 * 4));
  float* bcombp          = (float*)(ws + take((size_t)4096 * 4));
  unsigned short* hbf    = (unsigned short*)(ws + take((size_t)8192 * 1024 * 2));
  unsigned short* winbf  = (unsigned short*)(ws + take((size_t)6144 * 1024 * 2));
  unsigned short* wspbf  = (unsigned short*)(ws + take((size_t)4096 * 512 * 2));
  unsigned short* wupTbf = (unsigned short*)(ws + take((size_t)2048 * 512 * 2));
  unsigned short* woutbf = (unsigned short*)(ws + take((size_t)1024 * 2048 * 2));
  unsigned short* wcombbf= (unsigned short*)(ws + take((size_t)4096 * 2048 * 2));
  unsigned short* projbf = (unsigned short*)(ws + take((size_t)8192 * 6144 * 2));
  unsigned short* mixbf  = (unsigned short*)(ws + take((size_t)8192 * 2048 * 2));

  hipMemsetAsync(cntp, 0, 256 * 4, stream);

  conv_f32_bf16<<<4096, 256, 0, stream>>>(hidden, hbf, 1048576);
  conv_f32_bf16<<<3072, 256, 0, stream>>>(w_in, winbf, 786432);
  conv_f32_bf16<<<1024, 256, 0, stream>>>(w_sp, wspbf, 262144);
  conv_f32_bf16<<<1024, 256, 0, stream>>>(w_out, woutbf, 262144);
  transpose_wup<<<4096, 256, 0, stream>>>(w_up, wupTbf);

  // projected = hidden @ in_proj_w^T + b_in   [8192, 6144] bf16
  gemm_bt<0><<<dim3(64, 48), 256, 0, stream>>>(hbf, winbf, projbf, nullptr, b_in, 8192, 6144, 1024);
  // Wcomb = Wsp @ Wup   [4096, 2048] bf16  (B = Wup^T as [2048,512])
  gemm_bt<1><<<dim3(32, 16), 256, 0, stream>>>(wspbf, wupTbf, wcombbf, nullptr, nullptr, 4096, 2048, 512);

  bcomb_kernel<<<1024, 256, 0, stream>>>(w_sp, b_sp, b_up, bcombp);
  sp0_kernel<<<1024, 256, 0, stream>>>(w_sp, b_sp, state0, sp0p);

  {
    const unsigned short* a0 = wcombbf;
    const float* a1 = bcombp;
    const float* a2 = sp0p;
    const unsigned short* a3 = projbf;
    unsigned short* a4 = mixbf;
    unsigned* a5 = cntp;
    void* args[] = {&a0, &a1, &a2, &a3, &a4, &a5};
    hipLaunchCooperativeKernel((const void*)scan_kernel, dim3(NBLK), dim3(256), args, 0, stream);
  }

  // out = mixed @ out_proj_w^T + b_out  -> fp32, remapped to [B,S,D]
  gemm_bt<2><<<dim3(64, 8), 256, 0, stream>>>(mixbf, woutbf, nullptr, out, b_out, 8192, 1024, 2048);
  final_state_kernel<<<128, 256, 0, stream>>>(w_up, b_up, mixbf, out + (size_t)8192 * 1024);
}

// Round 16
// 6873.502 us; speedup vs baseline: 3.2989x; 1.0192x over previous
//
#include <hip/hip_runtime.h>
#include <hip/hip_bf16.h>

// Problem: B=4, S=2048, D=1024, INNER=2048, STATE=512.
// out = out_proj(scan(in_proj(hidden)));  scan folded via Wcomb = Wsp @ Wup.
// Round 16 = round-15 (PASS, 7.01ms) + LLC request-pressure reduction in the
// sync path: (a) wave0-only counter poll + __syncthreads release (r5-proven;
// poll traffic /4), (b) publish as 8x8B returning swaps (r10-proven; /2).
// Everything else byte-identical to r15.
// CONVICTED (do not reintroduce): A-fragments in VGPRs (r7/r8/r14);
// bulk staging via 8B atomic loads (r10/r11: bypasses XCD L2 -> 256x traffic).

#define S_LEN 2048
#define NBATCH 4
#define NBLK 256
#define LSTR 2056  // padded LDS row stride in bf16 (4112 B, 16B-aligned)

typedef __attribute__((ext_vector_type(4))) float f32x4;
typedef __attribute__((ext_vector_type(8))) short bf16x8;

__device__ __forceinline__ unsigned short f2bf(float f) {
  unsigned u = __builtin_bit_cast(unsigned, f);
  u += 0x7FFFu + ((u >> 16) & 1u);
  return (unsigned short)(u >> 16);
}
__device__ __forceinline__ float b2f(unsigned short s) { return __builtin_bit_cast(float, (unsigned)s << 16); }

__device__ __forceinline__ float wave_sum64(float v) {
#pragma unroll
  for (int m = 32; m >= 1; m >>= 1) v += __shfl_xor(v, m, 64);
  return v;
}

#define WAIT_VM0()   asm volatile("s_waitcnt vmcnt(0)" ::: "memory")
#define WAIT_LGKM0() asm volatile("s_waitcnt lgkmcnt(0)" ::: "memory")

// ---------------- fp32 -> bf16 convert (8 elems/thread) ----------------
__global__ void conv_f32_bf16(const float* __restrict__ in, unsigned short* __restrict__ out, int n8) {
  int g = blockIdx.x * 256 + threadIdx.x;
  if (g >= n8) return;
  const float4* p = (const float4*)in + 2 * (size_t)g;
  float4 a = p[0], b = p[1];
  uint4 o;
  o.x = (unsigned)f2bf(a.x) | ((unsigned)f2bf(a.y) << 16);
  o.y = (unsigned)f2bf(a.z) | ((unsigned)f2bf(a.w) << 16);
  o.z = (unsigned)f2bf(b.x) | ((unsigned)f2bf(b.y) << 16);
  o.w = (unsigned)f2bf(b.z) | ((unsigned)f2bf(b.w) << 16);
  ((uint4*)out)[g] = o;
}

// ---------------- Wup [512][2048] -> WupT bf16 [2048][512] ----------------
__global__ void transpose_wup(const float* __restrict__ in, unsigned short* __restrict__ out) {
  int g = blockIdx.x * 256 + threadIdx.x; // over 2048*512
  int i = g >> 9, k = g & 511;
  out[g] = f2bf(in[(size_t)k * 2048 + i]);
}

// ---------------- b_comb[j] = b_sp[j] + sum_k Wsp[j,k]*b_up[k] ----------------
__global__ void bcomb_kernel(const float* __restrict__ wsp, const float* __restrict__ bsp,
                             const float* __restrict__ bup, float* __restrict__ bcomb) {
  int wv = (blockIdx.x * 256 + threadIdx.x) >> 6;
  int lane = threadIdx.x & 63;
  if (wv >= 4096) return;
  float s = 0.f;
  for (int k = lane; k < 512; k += 64) s += wsp[(size_t)wv * 512 + k] * bup[k];
  s = wave_sum64(s);
  if (lane == 0) bcomb[wv] = s + bsp[wv];
}

// ---------------- sp0[b][j] = b_sp[j] + sum_k state0[b,k]*Wsp[j,k] ----------------
__global__ void sp0_kernel(const float* __restrict__ wsp, const float* __restrict__ bsp,
                           const float* __restrict__ state0, float* __restrict__ sp0) {
  int wv = (blockIdx.x * 256 + threadIdx.x) >> 6;
  int lane = threadIdx.x & 63;
  if (wv >= 4096) return;
  float acc[NBATCH] = {0.f, 0.f, 0.f, 0.f};
  for (int k = lane; k < 512; k += 64) {
    float w = wsp[(size_t)wv * 512 + k];
#pragma unroll
    for (int bb = 0; bb < NBATCH; ++bb) acc[bb] += state0[bb * 512 + k] * w;
  }
#pragma unroll
  for (int bb = 0; bb < NBATCH; ++bb) acc[bb] = wave_sum64(acc[bb]);
  if (lane == 0) {
    float b = bsp[wv];
#pragma unroll
    for (int bb = 0; bb < NBATCH; ++bb) sp0[bb * 4096 + wv] = acc[bb] + b;
  }
}

// ---------------- final_state[b][j] = b_up[j] + sum_i mixed[2047,b,i]*Wup[j,i] ----------------
__global__ void final_state_kernel(const float* __restrict__ wup, const float* __restrict__ bup,
                                   const unsigned short* __restrict__ mixedg, float* __restrict__ dst) {
  int wv = (blockIdx.x * 256 + threadIdx.x) >> 6;
  int lane = threadIdx.x & 63;
  if (wv >= 512) return;
  float acc[NBATCH] = {0.f, 0.f, 0.f, 0.f};
  for (int i = lane; i < 2048; i += 64) {
    float w = wup[(size_t)wv * 2048 + i];
#pragma unroll
    for (int bb = 0; bb < NBATCH; ++bb)
      acc[bb] += b2f(mixedg[((size_t)2047 * 4 + bb) * 2048 + i]) * w;
  }
#pragma unroll
  for (int bb = 0; bb < NBATCH; ++bb) acc[bb] = wave_sum64(acc[bb]);
  if (lane == 0) {
    float b = bup[wv];
#pragma unroll
    for (int bb = 0; bb < NBATCH; ++bb) dst[bb * 512 + wv] = acc[bb] + b;
  }
}

// ---------------- bf16 BT-GEMM: C[M,N] = A[M,K] @ B[N,K]^T (+bias) ----------------
// MODE 0: bf16 out + bias; MODE 1: bf16 out, no bias; MODE 2: fp32 out, bias,
// row remap m=s*4+b -> out[b][s][n] (S=2048, N=1024 hardcoded for out_proj).
template <int MODE>
__global__ __launch_bounds__(256) void gemm_bt(
    const unsigned short* __restrict__ A, const unsigned short* __restrict__ B,
    unsigned short* __restrict__ Cbf, float* __restrict__ Cf32,
    const float* __restrict__ bias, int M, int N, int K) {
  const int tm = blockIdx.x * 128, tn = blockIdx.y * 128;
  __shared__ __align__(16) unsigned short At[128][72];
  __shared__ __align__(16) unsigned short Bt[128][72];
  const int tid = threadIdx.x, lane = tid & 63, w = tid >> 6;
  const int wm = (w >> 1) * 64, wn = (w & 1) * 64;
  f32x4 acc[4][4];
#pragma unroll
  for (int a = 0; a < 4; ++a)
#pragma unroll
    for (int b = 0; b < 4; ++b) acc[a][b] = (f32x4)0.f;

  for (int k0 = 0; k0 < K; k0 += 64) {
#pragma unroll
    for (int it = 0; it < 4; ++it) {
      int c = tid + it * 256;
      int r = c >> 3, kp = (c & 7) * 8;
      *(uint4*)&At[r][kp] = *(const uint4*)&A[(size_t)(tm + r) * K + k0 + kp];
      *(uint4*)&Bt[r][kp] = *(const uint4*)&B[(size_t)(tn + r) * K + k0 + kp];
    }
    __syncthreads();
#pragma unroll
    for (int kk = 0; kk < 2; ++kk) {
      bf16x8 af[4], bfr[4];
#pragma unroll
      for (int fm = 0; fm < 4; ++fm)
        af[fm] = *(const bf16x8*)&At[wm + fm * 16 + (lane & 15)][(kk << 5) + ((lane >> 4) << 3)];
#pragma unroll
      for (int fn = 0; fn < 4; ++fn)
        bfr[fn] = *(const bf16x8*)&Bt[wn + fn * 16 + (lane & 15)][(kk << 5) + ((lane >> 4) << 3)];
#pragma unroll
      for (int fm = 0; fm < 4; ++fm)
#pragma unroll
        for (int fn = 0; fn < 4; ++fn)
          acc[fm][fn] = __builtin_amdgcn_mfma_f32_16x16x32_bf16(af[fm], bfr[fn], acc[fm][fn], 0, 0, 0);
    }
    __syncthreads();
  }
  // epilogue
  float bv[4];
#pragma unroll
  for (int fn = 0; fn < 4; ++fn) {
    if constexpr (MODE != 1) bv[fn] = bias[tn + wn + fn * 16 + (lane & 15)];
    else bv[fn] = 0.f;
  }
#pragma unroll
  for (int fm = 0; fm < 4; ++fm)
#pragma unroll
    for (int fn = 0; fn < 4; ++fn)
#pragma unroll
      for (int r = 0; r < 4; ++r) {
        int row = tm + wm + fm * 16 + ((lane >> 4) << 2) + r;
        int col = tn + wn + fn * 16 + (lane & 15);
        float v = acc[fm][fn][r] + bv[fn];
        if constexpr (MODE == 2) {
          Cf32[(size_t)(((row & 3) << 11) + (row >> 2)) * 1024 + col] = v;
        } else {
          Cbf[(size_t)row * N + col] = f2bf(v);
        }
      }
}

// ---------------- persistent scan kernel (4 waves per block) ----------------
// 256 blocks x 256 threads, 1 block/CU. Block b owns INNER slice [8b, 8b+8).
// K-split across waves: wave w stages B-columns [512w,512w+512) of mixed_{t-1}
// and computes MFMAs m in [16w,16w+16) over that quarter. Partial sums ->
// spbufp[w]; __syncthreads; wave0 reduces, nonlinearity, publishes 8 x 8B
// RETURNING atomic swaps, vmcnt drain, 8-SPREAD counter add; wave0 ALONE polls
// the 8 counters; __syncthreads releases waves 1-3 (poll traffic /4).
__global__ __launch_bounds__(256, 1) void scan_kernel(
    const unsigned short* __restrict__ wcombg,  // [4096][2048] bf16
    const float* __restrict__ bcombg,           // [4096]
    const float* __restrict__ sp0g,             // [4][4096]
    const unsigned short* __restrict__ projg,   // [8192][6144] bf16, m=b*2048+s
    unsigned short* __restrict__ mixedg,        // [2048][4][2048] bf16
    unsigned int* __restrict__ cnt)             // 8 counters, 128B apart, zeroed
{
  __shared__ __align__(16) unsigned short wcomb_lds[16][LSTR];  // 65.8 KB
  __shared__ __align__(16) unsigned short mixed_lds[5][LSTR];   // 20.6 KB, row4 = zeros
  __shared__ __align__(16) float spbufp[4][16][4];              // per-wave partials
  __shared__ __align__(16) float bcomb_lds[16];
  __shared__ __align__(16) unsigned short nlbuf[4][8];

  const int tid = threadIdx.x, bid = blockIdx.x;
  const int lane = tid & 63, w = tid >> 6;
  const int I0 = bid * 8;
  const int col = lane & 15;            // MFMA row/col index
  const int krow = (lane >> 4) << 3;    // MFMA k-subgroup offset
  const int m0 = w << 4;                // wave's MFMA k-chunk start

  // ---- prologue: stage Wcomb slice (u rows I0.., g rows 2048+I0..), 256 thr ----
  for (int c = tid; c < 4096; c += 256) {
    int r = c >> 8, kp = (c & 255) << 3;
    int gj = (r < 8) ? (I0 + r) : (2048 + I0 + r - 8);
    *(uint4*)&wcomb_lds[r][kp] = *(const uint4*)&wcombg[((size_t)gj << 11) + kp];
  }
  // zero pad row (B-fragment source for unused MFMA cols 4..15)
  {
    uint4 z; z.x = 0; z.y = 0; z.z = 0; z.w = 0;
    ((uint4*)&mixed_lds[4][0])[tid & 255] = z;
  }
  if (tid < 16) bcomb_lds[tid] = bcombg[(tid < 8) ? (I0 + tid) : (2048 + I0 + tid - 8)];

  // ---- prologue: t=0 tokens + sp0 into registers (wave0 lanes 0..31) ----
  unsigned short rtu = 0, rtg = 0, rtv = 0;
  float su0 = 0.f, sg0 = 0.f;
  if (tid < 32) {
    const int i = tid & 7, bb = tid >> 3;
    size_t base = (size_t)(bb * 2048) * 6144 + I0 + i;
    rtu = projg[base];
    rtg = projg[base + 2048];
    rtv = projg[base + 4096];
    su0 = sp0g[bb * 4096 + I0 + i];
    sg0 = sp0g[bb * 4096 + 2048 + I0 + i];
  }
  __syncthreads();  // wcomb + pad row + bcomb ready for all waves

  const unsigned short* arow = &wcomb_lds[col][0];
  const unsigned short* brow = &mixed_lds[(col < 4) ? col : 4][0];

#pragma unroll 1
  for (int t = 0; t < S_LEN; ++t) {
    if (t > 0) {
      // ---- stage own K-quarter of mixed_{t-1}: wave w covers k [512w,512w+512) ----
      {
        const uint4* src = (const uint4*)(mixedg + ((size_t)(t - 1) << 13));
#pragma unroll
        for (int c = 0; c < 4; ++c) {
          int u = tid + (c << 8);
          uint4 v = src[u];
          *(uint4*)&mixed_lds[u >> 8][(u & 255) << 3] = v;
        }
      }
      WAIT_LGKM0();  // own quarter's LDS writes complete (same wave)

      // ---- dot over own quarter: m in [m0, m0+16), 4 independent chains ----
      f32x4 ac0 = (f32x4)0.f, ac1 = (f32x4)0.f, ac2 = (f32x4)0.f, ac3 = (f32x4)0.f;
#pragma unroll
      for (int mm = 0; mm < 16; mm += 4) {
        const int m = m0 + mm;
        bf16x8 a0 = *(const bf16x8*)&arow[(m << 5) + krow];
        bf16x8 b0 = *(const bf16x8*)&brow[(m << 5) + krow];
        ac0 = __builtin_amdgcn_mfma_f32_16x16x32_bf16(a0, b0, ac0, 0, 0, 0);
        bf16x8 a1 = *(const bf16x8*)&arow[((m + 1) << 5) + krow];
        bf16x8 b1 = *(const bf16x8*)&brow[((m + 1) << 5) + krow];
        ac1 = __builtin_amdgcn_mfma_f32_16x16x32_bf16(a1, b1, ac1, 0, 0, 0);
        bf16x8 a2 = *(const bf16x8*)&arow[((m + 2) << 5) + krow];
        bf16x8 b2 = *(const bf16x8*)&brow[((m + 2) << 5) + krow];
        ac2 = __builtin_amdgcn_mfma_f32_16x16x32_bf16(a2, b2, ac2, 0, 0, 0);
        bf16x8 a3 = *(const bf16x8*)&arow[((m + 3) << 5) + krow];
        bf16x8 b3 = *(const bf16x8*)&brow[((m + 3) << 5) + krow];
        ac3 = __builtin_amdgcn_mfma_f32_16x16x32_bf16(a3, b3, ac3, 0, 0, 0);
      }
      f32x4 accT = (ac0 + ac1) + (ac2 + ac3);
      if (col < 4) {
#pragma unroll
        for (int r = 0; r < 4; ++r) spbufp[w][((lane >> 4) << 2) + r][col] = accT[r];
      }
    }
    __syncthreads();  // spbufp[0..3] ready

    // ---- nonlinearity (wave0 lanes 0..31): reduce 4 partials + bias ----
    if (tid < 32) {
      float su = su0, sg = sg0;
      const int i = tid & 7, bb = tid >> 3;
      if (t > 0) {
        su = (spbufp[0][i][bb] + spbufp[1][i][bb]) +
             (spbufp[2][i][bb] + spbufp[3][i][bb]) + bcomb_lds[i];
        sg = (spbufp[0][8 + i][bb] + spbufp[1][8 + i][bb]) +
             (spbufp[2][8 + i][bb] + spbufp[3][8 + i][bb]) + bcomb_lds[8 + i];
      }
      float tu = b2f(rtu), tg = b2f(rtg), tv = b2f(rtv);
      float cand = tanhf(tu + su);
      float gate = 1.0f / (1.0f + expf(-(tg + sg)));
      float mix = gate * cand + (1.0f - gate) * tanhf(tv);
      nlbuf[bb][i] = f2bf(mix);
    }

    if (w == 0) {
      WAIT_LGKM0();  // nlbuf + spbufp reads complete within wave 0
      // ---- publish slice: 8 x 8B RETURNING atomic swaps (performed at LLC) ----
      if (tid < 8) {
        const int bb = tid >> 1, half = tid & 1;
        unsigned long long val = *(const unsigned long long*)&nlbuf[bb][half * 4];
        unsigned long long* dst =
            (unsigned long long*)(mixedg + ((size_t)t * 4 + bb) * 2048 + I0) + half;
        unsigned long long old = __hip_atomic_exchange(dst, val,
                                                       __ATOMIC_RELAXED, __HIP_MEMORY_SCOPE_AGENT);
        asm volatile("" :: "v"((unsigned)old));  // keep returning form live (sc0)
      }
      if (t < S_LEN - 1) {
        WAIT_VM0();  // swaps performed at LLC
        if (tid == 0)
          __hip_atomic_fetch_add(&cnt[(bid & 7) << 5], 1u,
                                 __ATOMIC_RELAXED, __HIP_MEMORY_SCOPE_AGENT);
        // ---- token prefetch for step t+1 (wave0, hidden under poll) ----
        if (tid < 32) {
          const int i = tid & 7, bb = tid >> 3;
          size_t base = (size_t)(bb * 2048 + t + 1) * 6144 + I0 + i;
          rtu = projg[base];
          rtg = projg[base + 2048];
          rtv = projg[base + 4096];
        }
        // ---- wave0 ALONE polls the 8 spread counters ----
        const unsigned tgt = (unsigned)(t + 1) << 8;  // 256*(t+1)
        for (;;) {
          unsigned v = (lane < 8)
              ? __hip_atomic_load(&cnt[lane << 5], __ATOMIC_RELAXED, __HIP_MEMORY_SCOPE_AGENT)
              : 0u;
          v += __shfl_xor(v, 1);
          v += __shfl_xor(v, 2);
          v += __shfl_xor(v, 4);
          if (__shfl(v, 0) >= tgt) break;
          __builtin_amdgcn_s_sleep(1);
        }
      }
    }
    if (t < S_LEN - 1) __syncthreads();  // release waves 1..3 after wave0's detect
  }
}

extern "C" void kernel_launch(void* const* d_in, const int* in_sizes, int n_in,
                              void* d_out, int out_size, void* d_ws, size_t ws_size,
                              hipStream_t stream) {
  (void)in_sizes; (void)n_in; (void)out_size; (void)ws_size;
  const float* hidden = (const float*)d_in[0];
  const float* state0 = (const float*)d_in[1];
  const float* w_in   = (const float*)d_in[2];
  const float* b_in   = (const float*)d_in[3];
  const float* w_sp   = (const float*)d_in[4];
  const float* b_sp   = (const float*)d_in[5];
  const float* w_out  = (const float*)d_in[6];
  const float* b_out  = (const float*)d_in[7];
  const float* w_up   = (const float*)d_in[8];
  const float* b_up   = (const float*)d_in[9];
  float* out = (float*)d_out;
  char* ws = (char*)d_ws;

  size_t o = 0;
  auto take = [&](size_t b) { size_t p = o; o += (b + 255) & ~(size_t)255; return p; };
  unsigned* cntp         = (unsigned*)(ws + take(256 * 4));
  float* sp0p            = (float*)(ws + take((size_t)4 * 4096 * 4));
  float* bcombp          = (float*)(ws + take((size_t)4096 * 4));
  unsigned short* hbf    = (unsigned short*)(ws + take((size_t)8192 * 1024 * 2));
  unsigned short* winbf  = (unsigned short*)(ws + take((size_t)6144 * 1024 * 2));
  unsigned short* wspbf  = (unsigned short*)(ws + take((size_t)4096 * 512 * 2));
  unsigned short* wupTbf = (unsigned short*)(ws + take((size_t)2048 * 512 * 2));
  unsigned short* woutbf = (unsigned short*)(ws + take((size_t)1024 * 2048 * 2));
  unsigned short* wcombbf= (unsigned short*)(ws + take((size_t)4096 * 2048 * 2));
  unsigned short* projbf = (unsigned short*)(ws + take((size_t)8192 * 6144 * 2));
  unsigned short* mixbf  = (unsigned short*)(ws + take((size_t)8192 * 2048 * 2));

  hipMemsetAsync(cntp, 0, 256 * 4, stream);

  conv_f32_bf16<<<4096, 256, 0, stream>>>(hidden, hbf, 1048576);
  conv_f32_bf16<<<3072, 256, 0, stream>>>(w_in, winbf, 786432);
  conv_f32_bf16<<<1024, 256, 0, stream>>>(w_sp, wspbf, 262144);
  conv_f32_bf16<<<1024, 256, 0, stream>>>(w_out, woutbf, 262144);
  transpose_wup<<<4096, 256, 0, stream>>>(w_up, wupTbf);

  // projected = hidden @ in_proj_w^T + b_in   [8192, 6144] bf16
  gemm_bt<0><<<dim3(64, 48), 256, 0, stream>>>(hbf, winbf, projbf, nullptr, b_in, 8192, 6144, 1024);
  // Wcomb = Wsp @ Wup   [4096, 2048] bf16  (B = Wup^T as [2048,512])
  gemm_bt<1><<<dim3(32, 16), 256, 0, stream>>>(wspbf, wupTbf, wcombbf, nullptr, nullptr, 4096, 2048, 512);

  bcomb_kernel<<<1024, 256, 0, stream>>>(w_sp, b_sp, b_up, bcombp);
  sp0_kernel<<<1024, 256, 0, stream>>>(w_sp, b_sp, state0, sp0p);

  {
    const unsigned short* a0 = wcombbf;
    const float* a1 = bcombp;
    const float* a2 = sp0p;
    const unsigned short* a3 = projbf;
    unsigned short* a4 = mixbf;
    unsigned* a5 = cntp;
    void* args[] = {&a0, &a1, &a2, &a3, &a4, &a5};
    hipLaunchCooperativeKernel((const void*)scan_kernel, dim3(NBLK), dim3(256), args, 0, stream);
  }

  // out = mixed @ out_proj_w^T + b_out  -> fp32, remapped to [B,S,D]
  gemm_bt<2><<<dim3(64, 8), 256, 0, stream>>>(mixbf, woutbf, nullptr, out, b_out, 8192, 1024, 2048);
  final_state_kernel<<<128, 256, 0, stream>>>(w_up, b_up, mixbf, out + (size_t)8192 * 1024);
}